// Round 2
// baseline (7172.012 us; speedup 1.0000x reference)
//
#include <hip/hip_runtime.h>
#include <hip/hip_bf16.h>
#include <math.h>

typedef __hip_bfloat16 bf16;

#define EPI_F32   0
#define EPI_BF16  1
#define EPI_GELU  2
#define EPI_RESID 3

// ---------- bf16 helpers (bit-level, exact) ----------
__device__ __forceinline__ float bf_lo(unsigned int w) { return __uint_as_float(w << 16); }
__device__ __forceinline__ float bf_hi(unsigned int w) { return __uint_as_float(w & 0xffff0000u); }
__device__ __forceinline__ unsigned short f2b_bits(float f) {
  unsigned int u = __float_as_uint(f);
  unsigned int r = (u + 0x7fffu + ((u >> 16) & 1u)) >> 16;   // RTNE
  return (unsigned short)r;
}
// unpack 8 bf16 (one uint4) -> 8 floats
__device__ __forceinline__ void unpack8(uint4 u, float* f) {
  unsigned int w0 = u.x, w1 = u.y, w2 = u.z, w3 = u.w;
  f[0] = bf_lo(w0); f[1] = bf_hi(w0);
  f[2] = bf_lo(w1); f[3] = bf_hi(w1);
  f[4] = bf_lo(w2); f[5] = bf_hi(w2);
  f[6] = bf_lo(w3); f[7] = bf_hi(w3);
}
// typed 8-element loaders -> f32
__device__ __forceinline__ void load8(const float* p, float* f) {
  float4 a = ((const float4*)p)[0];
  float4 b = ((const float4*)p)[1];
  f[0] = a.x; f[1] = a.y; f[2] = a.z; f[3] = a.w;
  f[4] = b.x; f[5] = b.y; f[6] = b.z; f[7] = b.w;
}
__device__ __forceinline__ void load8(const bf16* p, float* f) {
  uint4 u = *(const uint4*)p;
  unpack8(u, f);
}

// ---------- generic tiled GEMM: C[m,n] = sum_k A[m,k] * B'[k,n] ----------
// TA: element type of A (float or bf16). B is always float (external weights).
// B_TRANS: B is (N x K) row-major (NT). else B is (K x N) row-major (NN).
// BM=BN=64, BK=32, 256 threads, 4x4 micro-tile per thread, f32 accumulate.
template<typename TA, bool B_TRANS, int EPI>
__device__ void gemm_core(const TA* __restrict__ A, int lda,
                          const float* __restrict__ B, int ldb,
                          void* __restrict__ C, int ldc,
                          const float* __restrict__ bias,
                          int m0, int n0, int K)
{
  __shared__ float As[32][68];   // [k][m], pad 68 (row start 16B-aligned: 68*4=272)
  __shared__ float Bs[32][68];   // [k][n]
  const int tid = threadIdx.x;

  float acc[4][4];
#pragma unroll
  for (int i = 0; i < 4; i++)
#pragma unroll
    for (int j = 0; j < 4; j++) acc[i][j] = 0.f;

  const int ar = tid >> 2;          // 0..63 (tile row)
  const int ak = (tid & 3) * 8;     // k offset 0/8/16/24
  const int br = tid >> 3;          // 0..31 (NN: k row)
  const int bn = (tid & 7) * 8;     // NN: n offset
  const int ml = (tid >> 4) * 4;
  const int nl = (tid & 15) * 4;

  for (int k0 = 0; k0 < K; k0 += 32) {
    {
      float f[8];
      load8(A + (size_t)(m0 + ar) * lda + (k0 + ak), f);
#pragma unroll
      for (int i = 0; i < 8; i++) As[ak + i][ar] = f[i];
    }
    if (B_TRANS) {
      float f[8];
      load8(B + (size_t)(n0 + ar) * ldb + (k0 + ak), f);
#pragma unroll
      for (int i = 0; i < 8; i++) Bs[ak + i][ar] = f[i];
    } else {
      float f[8];
      load8(B + (size_t)(k0 + br) * ldb + (n0 + bn), f);
#pragma unroll
      for (int i = 0; i < 8; i++) Bs[br][bn + i] = f[i];
    }
    __syncthreads();
#pragma unroll
    for (int kk = 0; kk < 32; kk++) {
      float4 a = *(const float4*)&As[kk][ml];
      float4 b = *(const float4*)&Bs[kk][nl];
      float av[4] = {a.x, a.y, a.z, a.w};
      float bv[4] = {b.x, b.y, b.z, b.w};
#pragma unroll
      for (int i = 0; i < 4; i++)
#pragma unroll
        for (int j = 0; j < 4; j++) acc[i][j] += av[i] * bv[j];
    }
    __syncthreads();
  }

  const int mg = m0 + ml;
  const int ng = n0 + nl;
#pragma unroll
  for (int i = 0; i < 4; i++) {
    if (EPI == EPI_F32) {
      float* Cf = (float*)C;
#pragma unroll
      for (int j = 0; j < 4; j++) Cf[(size_t)(mg + i) * ldc + ng + j] = acc[i][j];
    } else if (EPI == EPI_RESID) {
      float* Cf = (float*)C;
#pragma unroll
      for (int j = 0; j < 4; j++) {
        size_t idx = (size_t)(mg + i) * ldc + ng + j;
        Cf[idx] = Cf[idx] + acc[i][j] + bias[ng + j];
      }
    } else {
      unsigned short us[4];
#pragma unroll
      for (int j = 0; j < 4; j++) {
        float v = acc[i][j];
        if (EPI == EPI_GELU) {
          v += bias[ng + j];
          v = 0.5f * v * (1.f + erff(v * 0.70710678118654752f));
        }
        us[j] = f2b_bits(v);
      }
      *(ushort4*)((bf16*)C + (size_t)(mg + i) * ldc + ng) = *(ushort4*)us;
    }
  }
}

template<typename TA, bool B_TRANS, int EPI>
__global__ __launch_bounds__(256) void gemm_kernel(const TA* __restrict__ A, int lda,
                                                   const float* __restrict__ B, int ldb,
                                                   void* __restrict__ C, int ldc,
                                                   const float* __restrict__ bias, int K)
{
  gemm_core<TA, B_TRANS, EPI>(A, lda, B, ldb, C, ldc, bias, blockIdx.y * 64, blockIdx.x * 64, K);
}

// ---------- batched QKV projection: per (type,n,k) pick head weight, NN GEMM ----------
__global__ __launch_bounds__(256) void qkv_kernel(const bf16* __restrict__ hin,
                                                  const float* __restrict__ Wq,
                                                  const float* __restrict__ Wk,
                                                  const float* __restrict__ Wv,
                                                  bf16* __restrict__ qkv,
                                                  const int* __restrict__ tptr)
{
  const int zb = blockIdx.z;
  const int type = zb / 12, rem = zb % 12, n = rem / 3, kh = rem % 3;
  const int phase = ((tptr[0] % 4) + 4) % 4;
  const int hid = (kh == 0) ? n
                : (kh == 1) ? 4 + (n + 2 * (phase & 1)) % 4
                            : 8 + (n + phase) % 4;
  const float* W = (type == 0 ? Wq : type == 1 ? Wk : Wv) + (size_t)hid * 896 * 128;
  bf16* out = qkv + ((size_t)type * 12 + n * 3 + kh) * 4096 * 128;
  gemm_core<bf16, false, EPI_BF16>(hin + n * 896, 3584, W, 128, out, 128, nullptr,
                                   blockIdx.y * 64, blockIdx.x * 64, 896);
}

// ---------- z = base (broadcast over n) + beta * delta (in place) ----------
__global__ __launch_bounds__(256) void zbuild_kernel(float* __restrict__ z,
                                                     const float* __restrict__ base,
                                                     const float* __restrict__ beta_p)
{
  const float beta = beta_p[0];
  const int m = blockIdx.y;
  const int nd = blockIdx.x * 256 + threadIdx.x;
  const int d = nd % 896;
  const size_t idx = (size_t)m * 3584 + nd;
  z[idx] = base[(size_t)m * 896 + d] + beta * z[idx];
}

// ---------- LayerNorm rows of length D (f32 in, bf16 out) ----------
__global__ __launch_bounds__(256) void ln_kernel(const float* __restrict__ in,
                                                 const float* __restrict__ g,
                                                 const float* __restrict__ bsh,
                                                 bf16* __restrict__ out, int D)
{
  __shared__ float row[3584];
  __shared__ float red[256];
  const int tid = threadIdx.x;
  const size_t base = (size_t)blockIdx.x * D;
  float s = 0.f;
  for (int i = tid; i < D; i += 256) { float v = in[base + i]; row[i] = v; s += v; }
  red[tid] = s; __syncthreads();
  for (int o = 128; o > 0; o >>= 1) { if (tid < o) red[tid] += red[tid + o]; __syncthreads(); }
  const float mean = red[0] / (float)D;
  __syncthreads();
  s = 0.f;
  for (int i = tid; i < D; i += 256) { float d = row[i] - mean; s += d * d; }
  red[tid] = s; __syncthreads();
  for (int o = 128; o > 0; o >>= 1) { if (tid < o) red[tid] += red[tid + o]; __syncthreads(); }
  const float inv = rsqrtf(red[0] / (float)D + 1e-5f);
  for (int i = tid; i < D; i += 256) {
    float v = (row[i] - mean) * inv * g[i] + bsh[i];
    *((unsigned short*)out + base + i) = f2b_bits(v);
  }
}

// ---------- flash attention, one WG per (qtile of 64, b*n*k); adds into z slots ----------
__global__ __launch_bounds__(256) void attn_kernel(const bf16* __restrict__ qkv,
                                                   float* __restrict__ z,
                                                   const int* __restrict__ tptr)
{
  __shared__ float ks[32][130];
  __shared__ float vs[32][130];
  __shared__ float Sm[64][33];
  __shared__ float mrun[64], lrun[64], alph[64];
  const int tid = threadIdx.x;
  const int qb = blockIdx.x;              // 0..15
  const int bnk = blockIdx.y;             // 0..47
  const int b = bnk / 12, rem = bnk % 12, n = rem / 3, kh = rem % 3;
  const int phase = ((tptr[0] % 4) + 4) % 4;
  const int slot = (kh == 0) ? 0 : (kh == 1) ? 1 + (phase & 1) : 3 + phase;
  const size_t HS = (size_t)12 * 4096 * 128;
  const size_t rowbase = ((size_t)(n * 3 + kh) * 4096 + (size_t)b * 1024) * 128;
  const bf16* qp = qkv + rowbase;
  const bf16* kp = qkv + HS + rowbase;
  const bf16* vp = qkv + 2 * HS + rowbase;
  const int my_r = tid >> 2;              // 0..63 query row in tile
  const int part = tid & 3;               // dim quarter
  const int my_c0 = part * 32;

  float qreg[32];
  {
    const bf16* src = qp + (size_t)(qb * 64 + my_r) * 128 + my_c0;
#pragma unroll
    for (int i = 0; i < 4; i++) {
      uint4 u = ((const uint4*)src)[i];
      unpack8(u, &qreg[i * 8]);
    }
  }
  float o[32];
#pragma unroll
  for (int i = 0; i < 32; i++) o[i] = 0.f;
  if (tid < 64) { mrun[tid] = -1e30f; lrun[tid] = 0.f; }

  const int ktmax = 2 * qb + 1;
  for (int kt = 0; kt <= ktmax; kt++) {
    {
      const int r = tid >> 3;
      const int c0 = (tid & 7) * 16;
      const bf16* ksrc = kp + (size_t)(kt * 32 + r) * 128 + c0;
      const bf16* vsrc = vp + (size_t)(kt * 32 + r) * 128 + c0;
#pragma unroll
      for (int i = 0; i < 2; i++) {
        float f[8];
        unpack8(((const uint4*)ksrc)[i], f);
#pragma unroll
        for (int j = 0; j < 8; j++) ks[r][c0 + i * 8 + j] = f[j];
        unpack8(((const uint4*)vsrc)[i], f);
#pragma unroll
        for (int j = 0; j < 8; j++) vs[r][c0 + i * 8 + j] = f[j];
      }
    }
    __syncthreads();
    // scores: each group of 4 lanes (same row) computes partial dots, butterfly-combines
    float sv[8];
    for (int j = 0; j < 32; j++) {
      float s = 0.f;
      const float* krow = &ks[j][my_c0];
#pragma unroll
      for (int d = 0; d < 32; d++) s += qreg[d] * krow[d];
      s += __shfl_xor(s, 1, 64);
      s += __shfl_xor(s, 2, 64);
      if ((j >> 3) == part) sv[j & 7] = s;
    }
#pragma unroll
    for (int j = 0; j < 8; j++) Sm[my_r][part * 8 + j] = sv[j] * 0.088388347648318447f;
    __syncthreads();
    // online softmax stats, one thread per row
    if (tid < 64) {
      const int r = tid;
      const int tq = qb * 64 + r;
      int nv = tq - kt * 32 + 1;
      nv = nv > 32 ? 32 : nv;
      float mt = -1e30f;
      for (int j = 0; j < nv; j++) mt = fmaxf(mt, Sm[r][j]);
      const float mold = mrun[r];
      const float mn = fmaxf(mold, mt);
      const float a = __expf(mold - mn);
      float ssum = 0.f;
      for (int j = 0; j < 32; j++) {
        float p = (j < nv) ? __expf(Sm[r][j] - mn) : 0.f;
        Sm[r][j] = p;
        ssum += p;
      }
      mrun[r] = mn;
      lrun[r] = lrun[r] * a + ssum;
      alph[r] = a;
    }
    __syncthreads();
    // PV accumulate
    const float a = alph[my_r];
#pragma unroll
    for (int d = 0; d < 32; d++) o[d] *= a;
    for (int j = 0; j < 32; j++) {
      const float p = Sm[my_r][j];
      const float* vrow = &vs[j][my_c0];
#pragma unroll
      for (int d = 0; d < 32; d++) o[d] += p * vrow[d];
    }
    __syncthreads();
  }
  const float linv = 1.f / lrun[my_r];
  float* dst = z + (size_t)(b * 1024 + qb * 64 + my_r) * 3584 + n * 896 + slot * 128 + my_c0;
#pragma unroll
  for (int d = 0; d < 32; d++) dst[d] += o[d] * linv;
}

// ---------------------------------------------------------------------------
extern "C" void kernel_launch(void* const* d_in, const int* in_sizes, int n_in,
                              void* d_out, int out_size, void* d_ws, size_t ws_size,
                              hipStream_t stream)
{
  const float* x        = (const float*)d_in[0];
  const int*   tptr     = (const int*)d_in[1];
  const float* enc_base = (const float*)d_in[2];
  const float* enc_A    = (const float*)d_in[3];
  const float* enc_B    = (const float*)d_in[4];
  const float* beta_p   = (const float*)d_in[5];
  const float* lnm_g    = (const float*)d_in[6];
  const float* lnm_b    = (const float*)d_in[7];
  const float* w1       = (const float*)d_in[8];
  const float* b1       = (const float*)d_in[9];
  const float* w2       = (const float*)d_in[10];
  const float* b2       = (const float*)d_in[11];
  const float* lna_g    = (const float*)d_in[12];
  const float* lna_b    = (const float*)d_in[13];
  const float* Wq       = (const float*)d_in[14];
  const float* Wk       = (const float*)d_in[15];
  const float* Wv       = (const float*)d_in[16];
  const float* dln_g    = (const float*)d_in[17];
  const float* dln_b    = (const float*)d_in[18];
  const float* down_w   = (const float*)d_in[19];
  const float* up_w     = (const float*)d_in[20];

  // workspace layout (liveness-based reuse), ~149 MB total
  // [0, 58.7MB)      z: 4096x3584 f32 (residual stream, live throughout)
  // [58.7, 117.4MB)  region A: basef (steps 1-4) | act chunk 8192x3584 bf16 (6-7) | qkv (9-10)
  // [117.4, 146.8MB) bufb: 16384x896 bf16 (zm/hin/c)
  // [146.8, 148.9MB) bufh: 4096x256 bf16 (h/r)
  char* ws = (char*)d_ws;
  float* z     = (float*)ws;
  char*  bufa  = ws + (size_t)58720256;
  float* basef = (float*)bufa;
  bf16*  act   = (bf16*)bufa;
  bf16*  qkv   = (bf16*)bufa;
  bf16*  bufb  = (bf16*)(ws + (size_t)117440512);
  bf16*  bufh  = (bf16*)(ws + (size_t)146800640);

  dim3 blk(256);
  // 1. base = x @ enc_base_w^T            (4096x896, K=1024)
  gemm_kernel<float, true, EPI_F32><<<dim3(14, 64), blk, 0, stream>>>(x, 1024, enc_base, 1024, basef, 896, nullptr, 1024);
  // 2. h = x @ enc_A_w^T                  (4096x256, K=1024)
  gemm_kernel<float, true, EPI_BF16><<<dim3(4, 64), blk, 0, stream>>>(x, 1024, enc_A, 1024, bufh, 256, nullptr, 1024);
  // 3. delta = h @ enc_B(flat)            (4096x3584, K=256) -> z
  gemm_kernel<bf16, false, EPI_F32><<<dim3(56, 64), blk, 0, stream>>>(bufh, 256, enc_B, 3584, z, 3584, nullptr, 256);
  // 4. z = base + beta*delta
  zbuild_kernel<<<dim3(14, 4096), blk, 0, stream>>>(z, basef, beta_p);
  // 5. zm = LN(z) over 896  (z viewed as [16384, 896])
  ln_kernel<<<dim3(16384), blk, 0, stream>>>(z, lnm_g, lnm_b, bufb, 896);
  // 6+7. mixer, chunked over rows to cap act buffer at 58.7MB:
  for (int c = 0; c < 2; c++) {
    const size_t ro = (size_t)c * 8192;
    // act = gelu(zm @ w1^T + b1)          (8192x3584, K=896)
    gemm_kernel<bf16, true, EPI_GELU><<<dim3(56, 128), blk, 0, stream>>>(bufb + ro * 896, 896, w1, 896, act, 3584, b1, 896);
    // z += act @ w2^T + b2                (8192x896, K=3584)
    gemm_kernel<bf16, true, EPI_RESID><<<dim3(14, 128), blk, 0, stream>>>(act, 3584, w2, 3584, z + ro * 896, 896, b2, 3584);
  }
  // 8. hin = LN(z) over 896
  ln_kernel<<<dim3(16384), blk, 0, stream>>>(z, lna_g, lna_b, bufb, 896);
  // 9. q,k,v projections (36 batched GEMMs 4096x128, K=896)
  qkv_kernel<<<dim3(2, 64, 36), blk, 0, stream>>>(bufb, Wq, Wk, Wv, qkv, tptr);
  // 10. causal attention, adds into z slots
  attn_kernel<<<dim3(16, 48), blk, 0, stream>>>(qkv, z, tptr);
  // 11. c = LN(z) over 3584
  ln_kernel<<<dim3(4096), blk, 0, stream>>>(z, dln_g, dln_b, bufb, 3584);
  // 12. r = c @ dec_down_w^T              (4096x256, K=3584)
  gemm_kernel<bf16, true, EPI_BF16><<<dim3(4, 64), blk, 0, stream>>>(bufb, 3584, down_w, 3584, bufh, 256, nullptr, 3584);
  // 13. y = r @ dec_up_w^T                (4096x1024, K=256) -> out (f32)
  gemm_kernel<bf16, true, EPI_F32><<<dim3(16, 64), blk, 0, stream>>>(bufh, 256, up_w, 256, (float*)d_out, 1024, nullptr, 256);
}

// Round 3
// 4116.218 us; speedup vs baseline: 1.7424x; 1.7424x over previous
//
#include <hip/hip_runtime.h>
#include <hip/hip_bf16.h>
#include <math.h>

typedef __hip_bfloat16 bf16;
typedef __attribute__((ext_vector_type(8))) short v8s;
typedef __attribute__((ext_vector_type(4))) float v4f;

#define EPI_F32    0
#define EPI_BF16   1
#define EPI_GELU   2
#define EPI_RESID  3
#define EPI_BCAST4 4
#define EPI_AXPY   5

// ---------- bf16 helpers (bit-level, exact) ----------
__device__ __forceinline__ float bf_lo(unsigned int w) { return __uint_as_float(w << 16); }
__device__ __forceinline__ float bf_hi(unsigned int w) { return __uint_as_float(w & 0xffff0000u); }
__device__ __forceinline__ unsigned short f2b_bits(float f) {
  unsigned int u = __float_as_uint(f);
  unsigned int r = (u + 0x7fffu + ((u >> 16) & 1u)) >> 16;   // RTNE
  return (unsigned short)r;
}
__device__ __forceinline__ void unpack8(uint4 u, float* f) {
  unsigned int w0 = u.x, w1 = u.y, w2 = u.z, w3 = u.w;
  f[0] = bf_lo(w0); f[1] = bf_hi(w0);
  f[2] = bf_lo(w1); f[3] = bf_hi(w1);
  f[4] = bf_lo(w2); f[5] = bf_hi(w2);
  f[6] = bf_lo(w3); f[7] = bf_hi(w3);
}
__device__ __forceinline__ void load8(const float* p, float* f) {
  float4 a = ((const float4*)p)[0];
  float4 b = ((const float4*)p)[1];
  f[0] = a.x; f[1] = a.y; f[2] = a.z; f[3] = a.w;
  f[4] = b.x; f[5] = b.y; f[6] = b.z; f[7] = b.w;
}

// ---------- weight conversion kernels ----------
__global__ __launch_bounds__(256) void cvt_kernel(const float* __restrict__ src,
                                                  bf16* __restrict__ dst, int n)
{
  int i = (blockIdx.x * 256 + threadIdx.x) * 8;
  if (i >= n) return;
  float f[8]; load8(src + i, f);
  unsigned short us[8];
#pragma unroll
  for (int j = 0; j < 8; j++) us[j] = f2b_bits(f[j]);
  *(uint4*)((unsigned short*)dst + i) = *(uint4*)us;
}

// transpose-convert: src f32 (batch, R, C) -> dst bf16 (batch, C, R). R,C multiples of 32.
__global__ __launch_bounds__(256) void cvt_t_kernel(const float* __restrict__ src,
                                                    bf16* __restrict__ dst, int R, int C)
{
  __shared__ float tile[32][33];
  const int c0 = blockIdx.x * 32, r0 = blockIdx.y * 32;
  const size_t bo = (size_t)blockIdx.z * R * C;
  const int tx = threadIdx.x & 31, ty = threadIdx.x >> 5;  // ty 0..7
#pragma unroll
  for (int i = 0; i < 4; i++) {
    int r = ty * 4 + i;
    tile[r][tx] = src[bo + (size_t)(r0 + r) * C + c0 + tx];
  }
  __syncthreads();
#pragma unroll
  for (int i = 0; i < 4; i++) {
    int r = ty * 4 + i;   // column index within tile -> row of dst
    *((unsigned short*)dst + bo + (size_t)(c0 + r) * R + r0 + tx) = f2b_bits(tile[tx][r]);
  }
}

// ---------- MFMA GEMM core: C[m,n] = sum_k A[m,k]*B[n,k]  (both row-major over K, NT) ----------
// 128x128 tile, BK=32, 256 threads = 4 waves, each wave 64x64 via 4x4 mfma_f32_16x16x32_bf16.
// LDS layout: row-major with stride 40 bf16 (80B): conflict-free for b128 frag reads
// (bank group = (5*row + chunk) % 8, uniform 8 lanes/group).
__device__ __forceinline__ void stage_tile(const bf16* __restrict__ src, int ld, int r0, int k0,
                                           bf16* lds, int tid)
{
#pragma unroll
  for (int t = 0; t < 2; t++) {
    int s = t * 256 + tid;
    int m = s >> 2, c = s & 3;
    uint4 u = *(const uint4*)(src + (size_t)(r0 + m) * ld + k0 + c * 8);
    *(uint4*)&lds[m * 40 + c * 8] = u;
  }
}
__device__ __forceinline__ void stage_tile(const float* __restrict__ src, int ld, int r0, int k0,
                                           bf16* lds, int tid)
{
#pragma unroll
  for (int t = 0; t < 2; t++) {
    int s = t * 256 + tid;
    int m = s >> 2, c = s & 3;
    float f[8]; load8(src + (size_t)(r0 + m) * ld + k0 + c * 8, f);
    unsigned short us[8];
#pragma unroll
    for (int j = 0; j < 8; j++) us[j] = f2b_bits(f[j]);
    *(uint4*)&lds[m * 40 + c * 8] = *(uint4*)us;
  }
}

template<typename TA, typename TB, int EPI>
__device__ void mfma_core(const TA* __restrict__ A, int lda,
                          const TB* __restrict__ B, int ldb,
                          void* __restrict__ C, int ldc,
                          const float* __restrict__ bias,
                          const float* __restrict__ beta_p,
                          int m0, int n0, int K)
{
  __shared__ bf16 As[128 * 40];
  __shared__ bf16 Bs[128 * 40];
  const int tid = threadIdx.x;
  const int lane = tid & 63, wave = tid >> 6;
  const int mw = (wave & 1) * 64, nw = (wave >> 1) * 64;
  const int row = lane & 15, kc = lane >> 4;

  v4f acc[4][4];
  const v4f vzero = {0.f, 0.f, 0.f, 0.f};
#pragma unroll
  for (int i = 0; i < 4; i++)
#pragma unroll
    for (int j = 0; j < 4; j++) acc[i][j] = vzero;

  for (int k0 = 0; k0 < K; k0 += 32) {
    stage_tile(A, lda, m0, k0, As, tid);
    stage_tile(B, ldb, n0, k0, Bs, tid);
    __syncthreads();
    v8s af[4], bfr[4];
#pragma unroll
    for (int i = 0; i < 4; i++)
      af[i] = *(const v8s*)&As[(mw + i * 16 + row) * 40 + kc * 8];
#pragma unroll
    for (int j = 0; j < 4; j++)
      bfr[j] = *(const v8s*)&Bs[(nw + j * 16 + row) * 40 + kc * 8];
#pragma unroll
    for (int i = 0; i < 4; i++)
#pragma unroll
      for (int j = 0; j < 4; j++)
        acc[i][j] = __builtin_amdgcn_mfma_f32_16x16x32_bf16(af[i], bfr[j], acc[i][j], 0, 0, 0);
    __syncthreads();
  }

  // epilogue: C/D frag mapping col=lane&15, row=(lane>>4)*4+i  [guide-verified]
  const int cl = lane & 15, rq = lane >> 4;
  const float beta = (EPI == EPI_AXPY) ? beta_p[0] : 0.f;
#pragma unroll
  for (int mi = 0; mi < 4; mi++) {
#pragma unroll
    for (int nj = 0; nj < 4; nj++) {
      const int col = n0 + nw + nj * 16 + cl;
#pragma unroll
      for (int i = 0; i < 4; i++) {
        const int r = m0 + mw + mi * 16 + rq * 4 + i;
        float v = acc[mi][nj][i];
        if (EPI == EPI_F32) {
          ((float*)C)[(size_t)r * ldc + col] = v;
        } else if (EPI == EPI_BF16) {
          ((unsigned short*)C)[(size_t)r * ldc + col] = f2b_bits(v);
        } else if (EPI == EPI_GELU) {
          v += bias[col];
          v = 0.5f * v * (1.f + erff(v * 0.70710678118654752f));
          ((unsigned short*)C)[(size_t)r * ldc + col] = f2b_bits(v);
        } else if (EPI == EPI_RESID) {
          float* Z = (float*)C;
          size_t idx = (size_t)r * ldc + col;
          Z[idx] = Z[idx] + v + bias[col];
        } else if (EPI == EPI_BCAST4) {
          float* Z = (float*)C;
#pragma unroll
          for (int rep = 0; rep < 4; rep++)
            Z[(size_t)r * 3584 + rep * 896 + col] = v;
        } else if (EPI == EPI_AXPY) {
          float* Z = (float*)C;
          size_t idx = (size_t)r * 3584 + col;
          Z[idx] = Z[idx] + beta * v;
        }
      }
    }
  }
}

template<typename TA, typename TB, int EPI>
__global__ __launch_bounds__(256) void mfma_gemm(const TA* __restrict__ A, int lda,
                                                 const TB* __restrict__ B, int ldb,
                                                 void* __restrict__ C, int ldc,
                                                 const float* __restrict__ bias,
                                                 const float* __restrict__ beta_p, int K)
{
  mfma_core<TA, TB, EPI>(A, lda, B, ldb, C, ldc, bias, beta_p,
                         blockIdx.y * 128, blockIdx.x * 128, K);
}

// ---------- batched QKV projection (NT with pre-transposed Wt[type][head][128][896]) ----------
__global__ __launch_bounds__(256) void qkv_mfma(const bf16* __restrict__ hin,
                                                const bf16* __restrict__ Wt,
                                                bf16* __restrict__ qkv,
                                                const int* __restrict__ tptr)
{
  const int zb = blockIdx.z;
  const int type = zb / 12, rem = zb % 12, n = rem / 3, kh = rem % 3;
  const int phase = ((tptr[0] % 4) + 4) % 4;
  const int hid = (kh == 0) ? n
                : (kh == 1) ? 4 + (n + 2 * (phase & 1)) % 4
                            : 8 + (n + phase) % 4;
  const bf16* B = Wt + ((size_t)type * 12 + hid) * 128 * 896;
  bf16* out = qkv + ((size_t)type * 12 + n * 3 + kh) * 4096 * 128;
  mfma_core<bf16, bf16, EPI_BF16>(hin + n * 896, 3584, B, 896, out, 128,
                                  nullptr, nullptr, blockIdx.y * 128, 0, 896);
}

// ---------- LayerNorm rows of length D (f32 in, bf16 out) ----------
__global__ __launch_bounds__(256) void ln_kernel(const float* __restrict__ in,
                                                 const float* __restrict__ g,
                                                 const float* __restrict__ bsh,
                                                 bf16* __restrict__ out, int D)
{
  __shared__ float row[3584];
  __shared__ float red[256];
  const int tid = threadIdx.x;
  const size_t base = (size_t)blockIdx.x * D;
  float s = 0.f;
  for (int i = tid; i < D; i += 256) { float v = in[base + i]; row[i] = v; s += v; }
  red[tid] = s; __syncthreads();
  for (int o = 128; o > 0; o >>= 1) { if (tid < o) red[tid] += red[tid + o]; __syncthreads(); }
  const float mean = red[0] / (float)D;
  __syncthreads();
  s = 0.f;
  for (int i = tid; i < D; i += 256) { float d = row[i] - mean; s += d * d; }
  red[tid] = s; __syncthreads();
  for (int o = 128; o > 0; o >>= 1) { if (tid < o) red[tid] += red[tid + o]; __syncthreads(); }
  const float inv = rsqrtf(red[0] / (float)D + 1e-5f);
  for (int i = tid; i < D; i += 256) {
    float v = (row[i] - mean) * inv * g[i] + bsh[i];
    *((unsigned short*)out + base + i) = f2b_bits(v);
  }
}

// ---------- flash attention (unchanged this round), adds into z slots ----------
__global__ __launch_bounds__(256) void attn_kernel(const bf16* __restrict__ qkv,
                                                   float* __restrict__ z,
                                                   const int* __restrict__ tptr)
{
  __shared__ float ks[32][130];
  __shared__ float vs[32][130];
  __shared__ float Sm[64][33];
  __shared__ float mrun[64], lrun[64], alph[64];
  const int tid = threadIdx.x;
  const int qb = blockIdx.x;              // 0..15
  const int bnk = blockIdx.y;             // 0..47
  const int b = bnk / 12, rem = bnk % 12, n = rem / 3, kh = rem % 3;
  const int phase = ((tptr[0] % 4) + 4) % 4;
  const int slot = (kh == 0) ? 0 : (kh == 1) ? 1 + (phase & 1) : 3 + phase;
  const size_t HS = (size_t)12 * 4096 * 128;
  const size_t rowbase = ((size_t)(n * 3 + kh) * 4096 + (size_t)b * 1024) * 128;
  const bf16* qp = qkv + rowbase;
  const bf16* kp = qkv + HS + rowbase;
  const bf16* vp = qkv + 2 * HS + rowbase;
  const int my_r = tid >> 2;
  const int part = tid & 3;
  const int my_c0 = part * 32;

  float qreg[32];
  {
    const bf16* src = qp + (size_t)(qb * 64 + my_r) * 128 + my_c0;
#pragma unroll
    for (int i = 0; i < 4; i++) {
      uint4 u = ((const uint4*)src)[i];
      unpack8(u, &qreg[i * 8]);
    }
  }
  float o[32];
#pragma unroll
  for (int i = 0; i < 32; i++) o[i] = 0.f;
  if (tid < 64) { mrun[tid] = -1e30f; lrun[tid] = 0.f; }

  const int ktmax = 2 * qb + 1;
  for (int kt = 0; kt <= ktmax; kt++) {
    {
      const int r = tid >> 3;
      const int c0 = (tid & 7) * 16;
      const bf16* ksrc = kp + (size_t)(kt * 32 + r) * 128 + c0;
      const bf16* vsrc = vp + (size_t)(kt * 32 + r) * 128 + c0;
#pragma unroll
      for (int i = 0; i < 2; i++) {
        float f[8];
        unpack8(((const uint4*)ksrc)[i], f);
#pragma unroll
        for (int j = 0; j < 8; j++) ks[r][c0 + i * 8 + j] = f[j];
        unpack8(((const uint4*)vsrc)[i], f);
#pragma unroll
        for (int j = 0; j < 8; j++) vs[r][c0 + i * 8 + j] = f[j];
      }
    }
    __syncthreads();
    float sv[8];
    for (int j = 0; j < 32; j++) {
      float s = 0.f;
      const float* krow = &ks[j][my_c0];
#pragma unroll
      for (int d = 0; d < 32; d++) s += qreg[d] * krow[d];
      s += __shfl_xor(s, 1, 64);
      s += __shfl_xor(s, 2, 64);
      if ((j >> 3) == part) sv[j & 7] = s;
    }
#pragma unroll
    for (int j = 0; j < 8; j++) Sm[my_r][part * 8 + j] = sv[j] * 0.088388347648318447f;
    __syncthreads();
    if (tid < 64) {
      const int r = tid;
      const int tq = qb * 64 + r;
      int nv = tq - kt * 32 + 1;
      nv = nv > 32 ? 32 : nv;
      float mt = -1e30f;
      for (int j = 0; j < nv; j++) mt = fmaxf(mt, Sm[r][j]);
      const float mold = mrun[r];
      const float mn = fmaxf(mold, mt);
      const float a = __expf(mold - mn);
      float ssum = 0.f;
      for (int j = 0; j < 32; j++) {
        float p = (j < nv) ? __expf(Sm[r][j] - mn) : 0.f;
        Sm[r][j] = p;
        ssum += p;
      }
      mrun[r] = mn;
      lrun[r] = lrun[r] * a + ssum;
      alph[r] = a;
    }
    __syncthreads();
    const float a = alph[my_r];
#pragma unroll
    for (int d = 0; d < 32; d++) o[d] *= a;
    for (int j = 0; j < 32; j++) {
      const float p = Sm[my_r][j];
      const float* vrow = &vs[j][my_c0];
#pragma unroll
      for (int d = 0; d < 32; d++) o[d] += p * vrow[d];
    }
    __syncthreads();
  }
  const float linv = 1.f / lrun[my_r];
  float* dst = z + (size_t)(b * 1024 + qb * 64 + my_r) * 3584 + n * 896 + slot * 128 + my_c0;
#pragma unroll
  for (int d = 0; d < 32; d++) dst[d] += o[d] * linv;
}

// ---------------------------------------------------------------------------
extern "C" void kernel_launch(void* const* d_in, const int* in_sizes, int n_in,
                              void* d_out, int out_size, void* d_ws, size_t ws_size,
                              hipStream_t stream)
{
  const float* x        = (const float*)d_in[0];
  const int*   tptr     = (const int*)d_in[1];
  const float* enc_base = (const float*)d_in[2];
  const float* enc_A    = (const float*)d_in[3];
  const float* enc_B    = (const float*)d_in[4];
  const float* beta_p   = (const float*)d_in[5];
  const float* lnm_g    = (const float*)d_in[6];
  const float* lnm_b    = (const float*)d_in[7];
  const float* w1       = (const float*)d_in[8];
  const float* b1       = (const float*)d_in[9];
  const float* w2       = (const float*)d_in[10];
  const float* b2       = (const float*)d_in[11];
  const float* lna_g    = (const float*)d_in[12];
  const float* lna_b    = (const float*)d_in[13];
  const float* Wq       = (const float*)d_in[14];
  const float* Wk       = (const float*)d_in[15];
  const float* Wv       = (const float*)d_in[16];
  const float* dln_g    = (const float*)d_in[17];
  const float* dln_b    = (const float*)d_in[18];
  const float* down_w   = (const float*)d_in[19];
  const float* up_w     = (const float*)d_in[20];

  // workspace (148.77 MB total, <= proven 148.9 MB):
  // [0, 58720256)                z: 4096x3584 f32 residual stream
  // [58720256, 96468992)         regionA: h/r (steps 2-3/12-13) | act 4096x3584 bf16 chunks | qkv bf16
  // [96468992, 125829120)        bufb: 16384x896 bf16 (zm/hin/c)
  // [125829120, 148766720)       bf16 weights: w1b, w2b, enc_Bt, Wt
  char* ws = (char*)d_ws;
  float* z      = (float*)ws;
  bf16*  hbuf   = (bf16*)(ws + (size_t)58720256);   // also r-buffer
  bf16*  act    = (bf16*)(ws + (size_t)58720256);
  bf16*  qkv    = (bf16*)(ws + (size_t)58720256);
  bf16*  bufb   = (bf16*)(ws + (size_t)96468992);
  bf16*  w1b    = (bf16*)(ws + (size_t)125829120);
  bf16*  w2b    = (bf16*)(ws + (size_t)132251648);
  bf16*  encBt  = (bf16*)(ws + (size_t)138674176);
  bf16*  Wt     = (bf16*)(ws + (size_t)140509184);  // [3][12][128][896]

  dim3 blk(256);
  // --- weight conversion (every call; inputs restored each timed launch) ---
  cvt_kernel<<<1568, blk, 0, stream>>>(w1, w1b, 3211264);
  cvt_kernel<<<1568, blk, 0, stream>>>(w2, w2b, 3211264);
  cvt_t_kernel<<<dim3(112, 8, 1), blk, 0, stream>>>(enc_B, encBt, 256, 3584);
  cvt_t_kernel<<<dim3(4, 28, 12), blk, 0, stream>>>(Wq, Wt,                      896, 128);
  cvt_t_kernel<<<dim3(4, 28, 12), blk, 0, stream>>>(Wk, Wt + (size_t)12*128*896, 896, 128);
  cvt_t_kernel<<<dim3(4, 28, 12), blk, 0, stream>>>(Wv, Wt + (size_t)24*128*896, 896, 128);

  // 1. z[:, rep*896+n] = (x @ enc_base_w^T)[:, n]   (4096x896, K=1024, bcast over 4 slots)
  mfma_gemm<float, float, EPI_BCAST4><<<dim3(7, 32), blk, 0, stream>>>(x, 1024, enc_base, 1024, z, 0, nullptr, nullptr, 1024);
  // 2. h = x @ enc_A_w^T                  (4096x256, K=1024)
  mfma_gemm<float, float, EPI_BF16><<<dim3(2, 32), blk, 0, stream>>>(x, 1024, enc_A, 1024, hbuf, 256, nullptr, nullptr, 1024);
  // 3. z += beta * (h @ enc_Bt^T)         (4096x3584, K=256)
  mfma_gemm<bf16, bf16, EPI_AXPY><<<dim3(28, 32), blk, 0, stream>>>(hbuf, 256, encBt, 256, z, 3584, nullptr, beta_p, 256);
  // 5. zm = LN(z) over 896
  ln_kernel<<<dim3(16384), blk, 0, stream>>>(z, lnm_g, lnm_b, bufb, 896);
  // 6+7. mixer, 4 chunks of 4096 rows (act buffer 29.4MB fits regionA)
  for (int c = 0; c < 4; c++) {
    const size_t ro = (size_t)c * 4096;
    mfma_gemm<bf16, bf16, EPI_GELU><<<dim3(28, 32), blk, 0, stream>>>(bufb + ro * 896, 896, w1b, 896, act, 3584, b1, nullptr, 896);
    mfma_gemm<bf16, bf16, EPI_RESID><<<dim3(7, 32), blk, 0, stream>>>(act, 3584, w2b, 3584, z + ro * 896, 896, b2, nullptr, 3584);
  }
  // 8. hin = LN(z) over 896
  ln_kernel<<<dim3(16384), blk, 0, stream>>>(z, lna_g, lna_b, bufb, 896);
  // 9. q,k,v projections (36 batched GEMMs 4096x128, K=896)
  qkv_mfma<<<dim3(1, 32, 36), blk, 0, stream>>>(bufb, Wt, qkv, tptr);
  // 10. causal attention, adds into z slots
  attn_kernel<<<dim3(16, 48), blk, 0, stream>>>(qkv, z, tptr);
  // 11. c = LN(z) over 3584
  ln_kernel<<<dim3(4096), blk, 0, stream>>>(z, dln_g, dln_b, bufb, 3584);
  // 12. r = c @ dec_down_w^T              (4096x256, K=3584)
  mfma_gemm<bf16, float, EPI_BF16><<<dim3(2, 32), blk, 0, stream>>>(bufb, 3584, down_w, 3584, hbuf, 256, nullptr, nullptr, 3584);
  // 13. y = r @ dec_up_w^T                (4096x1024, K=256) -> out (f32)
  mfma_gemm<bf16, float, EPI_F32><<<dim3(8, 32), blk, 0, stream>>>(hbuf, 256, up_w, 256, (float*)d_out, 1024, nullptr, nullptr, 256);
}

// Round 4
// 1319.959 us; speedup vs baseline: 5.4335x; 3.1184x over previous
//
#include <hip/hip_runtime.h>
#include <hip/hip_bf16.h>
#include <math.h>

typedef __hip_bfloat16 bf16;
typedef __attribute__((ext_vector_type(8))) short v8s;
typedef __attribute__((ext_vector_type(4))) float v4f;

#define EPI_F32    0
#define EPI_BF16   1
#define EPI_GELU   2
#define EPI_RESID  3
#define EPI_BCAST4 4
#define EPI_AXPY   5

// ---------- bf16 helpers (bit-level, exact) ----------
__device__ __forceinline__ float bf_lo(unsigned int w) { return __uint_as_float(w << 16); }
__device__ __forceinline__ float bf_hi(unsigned int w) { return __uint_as_float(w & 0xffff0000u); }
__device__ __forceinline__ unsigned short f2b_bits(float f) {
  unsigned int u = __float_as_uint(f);
  unsigned int r = (u + 0x7fffu + ((u >> 16) & 1u)) >> 16;   // RTNE
  return (unsigned short)r;
}
__device__ __forceinline__ void unpack8(uint4 u, float* f) {
  unsigned int w0 = u.x, w1 = u.y, w2 = u.z, w3 = u.w;
  f[0] = bf_lo(w0); f[1] = bf_hi(w0);
  f[2] = bf_lo(w1); f[3] = bf_hi(w1);
  f[4] = bf_lo(w2); f[5] = bf_hi(w2);
  f[6] = bf_lo(w3); f[7] = bf_hi(w3);
}
__device__ __forceinline__ void load8(const float* p, float* f) {
  float4 a = ((const float4*)p)[0];
  float4 b = ((const float4*)p)[1];
  f[0] = a.x; f[1] = a.y; f[2] = a.z; f[3] = a.w;
  f[4] = b.x; f[5] = b.y; f[6] = b.z; f[7] = b.w;
}

// ---------- weight conversion kernels ----------
__global__ __launch_bounds__(256) void cvt_kernel(const float* __restrict__ src,
                                                  bf16* __restrict__ dst, int n)
{
  int i = (blockIdx.x * 256 + threadIdx.x) * 8;
  if (i >= n) return;
  float f[8]; load8(src + i, f);
  unsigned short us[8];
#pragma unroll
  for (int j = 0; j < 8; j++) us[j] = f2b_bits(f[j]);
  *(uint4*)((unsigned short*)dst + i) = *(uint4*)us;
}

// transpose-convert: src f32 (batch, R, C) -> dst bf16 (batch, C, R). R,C multiples of 32.
__global__ __launch_bounds__(256) void cvt_t_kernel(const float* __restrict__ src,
                                                    bf16* __restrict__ dst, int R, int C)
{
  __shared__ float tile[32][33];
  const int c0 = blockIdx.x * 32, r0 = blockIdx.y * 32;
  const size_t bo = (size_t)blockIdx.z * R * C;
  const int tx = threadIdx.x & 31, ty = threadIdx.x >> 5;  // ty 0..7
#pragma unroll
  for (int i = 0; i < 4; i++) {
    int r = ty * 4 + i;
    tile[r][tx] = src[bo + (size_t)(r0 + r) * C + c0 + tx];
  }
  __syncthreads();
#pragma unroll
  for (int i = 0; i < 4; i++) {
    int r = ty * 4 + i;   // column index within tile -> row of dst
    *((unsigned short*)dst + bo + (size_t)(c0 + r) * R + r0 + tx) = f2b_bits(tile[tx][r]);
  }
}

// bf16 transpose: v [12][4096][128] -> vt [12][128][4096], 64x64 tiles via f32 LDS
__global__ __launch_bounds__(256) void vt_kernel(const bf16* __restrict__ v,
                                                 bf16* __restrict__ vt)
{
  __shared__ float tile[64][65];
  const int h = blockIdx.z;
  const int t0 = blockIdx.x * 64, d0 = blockIdx.y * 64;
  const bf16* src = v + (size_t)h * 4096 * 128;
  bf16* dst = vt + (size_t)h * 128 * 4096;
  const int tid = threadIdx.x;
#pragma unroll
  for (int tt = 0; tt < 2; tt++) {
    int s = tt * 256 + tid;
    int r = s >> 3, c0 = (s & 7) * 8;
    float f[8];
    uint4 u = *(const uint4*)(src + (size_t)(t0 + r) * 128 + d0 + c0);
    unpack8(u, f);
#pragma unroll
    for (int j = 0; j < 8; j++) tile[r][c0 + j] = f[j];
  }
  __syncthreads();
#pragma unroll
  for (int tt = 0; tt < 2; tt++) {
    int s = tt * 256 + tid;
    int dr = s >> 3, c0 = (s & 7) * 8;
    unsigned short us[8];
#pragma unroll
    for (int j = 0; j < 8; j++) us[j] = f2b_bits(tile[c0 + j][dr]);
    *(uint4*)((unsigned short*)dst + (size_t)(d0 + dr) * 4096 + t0 + c0) = *(uint4*)us;
  }
}

// ---------- MFMA GEMM core (unchanged from R3, proven) ----------
__device__ __forceinline__ void stage_tile(const bf16* __restrict__ src, int ld, int r0, int k0,
                                           bf16* lds, int tid)
{
#pragma unroll
  for (int t = 0; t < 2; t++) {
    int s = t * 256 + tid;
    int m = s >> 2, c = s & 3;
    uint4 u = *(const uint4*)(src + (size_t)(r0 + m) * ld + k0 + c * 8);
    *(uint4*)&lds[m * 40 + c * 8] = u;
  }
}
__device__ __forceinline__ void stage_tile(const float* __restrict__ src, int ld, int r0, int k0,
                                           bf16* lds, int tid)
{
#pragma unroll
  for (int t = 0; t < 2; t++) {
    int s = t * 256 + tid;
    int m = s >> 2, c = s & 3;
    float f[8]; load8(src + (size_t)(r0 + m) * ld + k0 + c * 8, f);
    unsigned short us[8];
#pragma unroll
    for (int j = 0; j < 8; j++) us[j] = f2b_bits(f[j]);
    *(uint4*)&lds[m * 40 + c * 8] = *(uint4*)us;
  }
}

template<typename TA, typename TB, int EPI>
__device__ void mfma_core(const TA* __restrict__ A, int lda,
                          const TB* __restrict__ B, int ldb,
                          void* __restrict__ C, int ldc,
                          const float* __restrict__ bias,
                          const float* __restrict__ beta_p,
                          int m0, int n0, int K)
{
  __shared__ bf16 As[128 * 40];
  __shared__ bf16 Bs[128 * 40];
  const int tid = threadIdx.x;
  const int lane = tid & 63, wave = tid >> 6;
  const int mw = (wave & 1) * 64, nw = (wave >> 1) * 64;
  const int row = lane & 15, kc = lane >> 4;

  v4f acc[4][4];
  const v4f vzero = {0.f, 0.f, 0.f, 0.f};
#pragma unroll
  for (int i = 0; i < 4; i++)
#pragma unroll
    for (int j = 0; j < 4; j++) acc[i][j] = vzero;

  for (int k0 = 0; k0 < K; k0 += 32) {
    stage_tile(A, lda, m0, k0, As, tid);
    stage_tile(B, ldb, n0, k0, Bs, tid);
    __syncthreads();
    v8s af[4], bfr[4];
#pragma unroll
    for (int i = 0; i < 4; i++)
      af[i] = *(const v8s*)&As[(mw + i * 16 + row) * 40 + kc * 8];
#pragma unroll
    for (int j = 0; j < 4; j++)
      bfr[j] = *(const v8s*)&Bs[(nw + j * 16 + row) * 40 + kc * 8];
#pragma unroll
    for (int i = 0; i < 4; i++)
#pragma unroll
      for (int j = 0; j < 4; j++)
        acc[i][j] = __builtin_amdgcn_mfma_f32_16x16x32_bf16(af[i], bfr[j], acc[i][j], 0, 0, 0);
    __syncthreads();
  }

  const int cl = lane & 15, rq = lane >> 4;
  const float beta = (EPI == EPI_AXPY) ? beta_p[0] : 0.f;
#pragma unroll
  for (int mi = 0; mi < 4; mi++) {
#pragma unroll
    for (int nj = 0; nj < 4; nj++) {
      const int col = n0 + nw + nj * 16 + cl;
#pragma unroll
      for (int i = 0; i < 4; i++) {
        const int r = m0 + mw + mi * 16 + rq * 4 + i;
        float v = acc[mi][nj][i];
        if (EPI == EPI_F32) {
          ((float*)C)[(size_t)r * ldc + col] = v;
        } else if (EPI == EPI_BF16) {
          ((unsigned short*)C)[(size_t)r * ldc + col] = f2b_bits(v);
        } else if (EPI == EPI_GELU) {
          v += bias[col];
          v = 0.5f * v * (1.f + erff(v * 0.70710678118654752f));
          ((unsigned short*)C)[(size_t)r * ldc + col] = f2b_bits(v);
        } else if (EPI == EPI_RESID) {
          float* Z = (float*)C;
          size_t idx = (size_t)r * ldc + col;
          Z[idx] = Z[idx] + v + bias[col];
        } else if (EPI == EPI_BCAST4) {
          float* Z = (float*)C;
#pragma unroll
          for (int rep = 0; rep < 4; rep++)
            Z[(size_t)r * 3584 + rep * 896 + col] = v;
        } else if (EPI == EPI_AXPY) {
          float* Z = (float*)C;
          size_t idx = (size_t)r * 3584 + col;
          Z[idx] = Z[idx] + beta * v;
        }
      }
    }
  }
}

template<typename TA, typename TB, int EPI>
__global__ __launch_bounds__(256) void mfma_gemm(const TA* __restrict__ A, int lda,
                                                 const TB* __restrict__ B, int ldb,
                                                 void* __restrict__ C, int ldc,
                                                 const float* __restrict__ bias,
                                                 const float* __restrict__ beta_p, int K)
{
  mfma_core<TA, TB, EPI>(A, lda, B, ldb, C, ldc, bias, beta_p,
                         blockIdx.y * 128, blockIdx.x * 128, K);
}

// ---------- batched QKV projection (NT with pre-transposed Wt[type][head][128][896]) ----------
__global__ __launch_bounds__(256) void qkv_mfma(const bf16* __restrict__ hin,
                                                const bf16* __restrict__ Wt,
                                                bf16* __restrict__ qkv,
                                                const int* __restrict__ tptr)
{
  const int zb = blockIdx.z;
  const int type = zb / 12, rem = zb % 12, n = rem / 3, kh = rem % 3;
  const int phase = ((tptr[0] % 4) + 4) % 4;
  const int hid = (kh == 0) ? n
                : (kh == 1) ? 4 + (n + 2 * (phase & 1)) % 4
                            : 8 + (n + phase) % 4;
  const bf16* B = Wt + ((size_t)type * 12 + hid) * 128 * 896;
  bf16* out = qkv + ((size_t)type * 12 + n * 3 + kh) * 4096 * 128;
  mfma_core<bf16, bf16, EPI_BF16>(hin + n * 896, 3584, B, 896, out, 128,
                                  nullptr, nullptr, blockIdx.y * 128, 0, 896);
}

// ---------- LayerNorm rows of length D (f32 in, bf16 out) ----------
__global__ __launch_bounds__(256) void ln_kernel(const float* __restrict__ in,
                                                 const float* __restrict__ g,
                                                 const float* __restrict__ bsh,
                                                 bf16* __restrict__ out, int D)
{
  __shared__ float row[3584];
  __shared__ float red[256];
  const int tid = threadIdx.x;
  const size_t base = (size_t)blockIdx.x * D;
  float s = 0.f;
  for (int i = tid; i < D; i += 256) { float v = in[base + i]; row[i] = v; s += v; }
  red[tid] = s; __syncthreads();
  for (int o = 128; o > 0; o >>= 1) { if (tid < o) red[tid] += red[tid + o]; __syncthreads(); }
  const float mean = red[0] / (float)D;
  __syncthreads();
  s = 0.f;
  for (int i = tid; i < D; i += 256) { float d = row[i] - mean; s += d * d; }
  red[tid] = s; __syncthreads();
  for (int o = 128; o > 0; o >>= 1) { if (tid < o) red[tid] += red[tid + o]; __syncthreads(); }
  const float inv = rsqrtf(red[0] / (float)D + 1e-5f);
  for (int i = tid; i < D; i += 256) {
    float v = (row[i] - mean) * inv * g[i] + bsh[i];
    *((unsigned short*)out + base + i) = f2b_bits(v);
  }
}

// ---------- MFMA flash attention ----------
// Grid (16, 48): one WG (4 waves) per (64-row q-tile, b*n*k head). Each wave owns 16 q rows.
// K tile [64][136] LDS, V^T tile [128][72] LDS, P strip per wave [16][72].
__global__ __launch_bounds__(256) void attn_mfma(const bf16* __restrict__ qkv,
                                                 const bf16* __restrict__ vt,
                                                 float* __restrict__ z,
                                                 const int* __restrict__ tptr)
{
  __shared__ bf16 Ks[64 * 136];
  __shared__ bf16 Vs[128 * 72];
  __shared__ bf16 Ps[4][16 * 72];
  const int tid = threadIdx.x;
  const int lane = tid & 63, wave = tid >> 6;
  const int cl = lane & 15, rq = lane >> 4;
  const int qb = 15 - blockIdx.x;          // heavy tiles dispatched first
  const int bnk = blockIdx.y;
  const int b = bnk / 12, rem = bnk % 12, n = rem / 3, kh = rem % 3;
  const int phase = ((tptr[0] % 4) + 4) % 4;
  const int slot = (kh == 0) ? 0 : (kh == 1) ? 1 + (phase & 1) : 3 + phase;
  const int head = n * 3 + kh;
  const size_t HS = (size_t)12 * 4096 * 128;
  const bf16* qp = qkv + ((size_t)head * 4096 + b * 1024) * 128;       // [t][128]
  const bf16* kp = qkv + HS + ((size_t)head * 4096 + b * 1024) * 128;  // [t][128]
  const bf16* vtp = vt + (size_t)head * 128 * 4096;                    // [d][4096]

  // Q fragments (A-layout): lane holds row cl of wave's 16, k-chunk rq*8
  v8s aq[4];
  {
    const bf16* qrow = qp + (size_t)(qb * 64 + wave * 16 + cl) * 128 + rq * 8;
#pragma unroll
    for (int c = 0; c < 4; c++) aq[c] = *(const v8s*)(qrow + c * 32);
  }
  v4f oacc[8];
  const v4f vzero = {0.f, 0.f, 0.f, 0.f};
#pragma unroll
  for (int c = 0; c < 8; c++) oacc[c] = vzero;
  float m_i[4] = {-1e30f, -1e30f, -1e30f, -1e30f};
  float l_i[4] = {0.f, 0.f, 0.f, 0.f};

  for (int kt = 0; kt <= qb; kt++) {
    __syncthreads();   // all waves done reading previous K/V tiles
    // stage K tile: 64 rows x 128 (stride 136)
#pragma unroll
    for (int t = 0; t < 4; t++) {
      int s = t * 256 + tid;
      int r = s >> 4, c0 = (s & 15) * 8;
      *(uint4*)&Ks[r * 136 + c0] = *(const uint4*)(kp + (size_t)(kt * 64 + r) * 128 + c0);
    }
    // stage V^T tile: 128 rows (d) x 64 (kp) (stride 72)
#pragma unroll
    for (int t = 0; t < 4; t++) {
      int s = t * 256 + tid;
      int d = s >> 3, c0 = (s & 7) * 8;
      *(uint4*)&Vs[d * 72 + c0] =
          *(const uint4*)(vtp + (size_t)d * 4096 + b * 1024 + kt * 64 + c0);
    }
    __syncthreads();

    // S = Q K^T : 4 blocks of 16 kpos, each accumulated over 4 k-chunks
    v4f s_acc[4];
#pragma unroll
    for (int blk = 0; blk < 4; blk++) {
      s_acc[blk] = vzero;
#pragma unroll
      for (int c = 0; c < 4; c++) {
        v8s bk = *(const v8s*)&Ks[(blk * 16 + cl) * 136 + c * 32 + rq * 8];
        s_acc[blk] = __builtin_amdgcn_mfma_f32_16x16x32_bf16(aq[c], bk, s_acc[blk], 0, 0, 0);
      }
    }
    // scale + causal mask (only last tile needs masking)
#pragma unroll
    for (int blk = 0; blk < 4; blk++)
#pragma unroll
      for (int i = 0; i < 4; i++) {
        float sv = s_acc[blk][i] * 0.088388347648318447f;
        if (kt == qb && (blk * 16 + cl) > (wave * 16 + rq * 4 + i)) sv = -1e30f;
        s_acc[blk][i] = sv;
      }
    // online softmax per row (rows rq*4+i, stats replicated across 16 cl lanes)
    float al[4];
#pragma unroll
    for (int i = 0; i < 4; i++) {
      float mx = fmaxf(fmaxf(s_acc[0][i], s_acc[1][i]), fmaxf(s_acc[2][i], s_acc[3][i]));
      mx = fmaxf(mx, __shfl_xor(mx, 1, 64));
      mx = fmaxf(mx, __shfl_xor(mx, 2, 64));
      mx = fmaxf(mx, __shfl_xor(mx, 4, 64));
      mx = fmaxf(mx, __shfl_xor(mx, 8, 64));
      const float mn = fmaxf(m_i[i], mx);
      al[i] = __expf(m_i[i] - mn);
      m_i[i] = mn;
      float ps = 0.f;
#pragma unroll
      for (int blk = 0; blk < 4; blk++) {
        float p = __expf(s_acc[blk][i] - mn);
        s_acc[blk][i] = p;
        ps += p;
      }
      ps += __shfl_xor(ps, 1, 64);
      ps += __shfl_xor(ps, 2, 64);
      ps += __shfl_xor(ps, 4, 64);
      ps += __shfl_xor(ps, 8, 64);
      l_i[i] = l_i[i] * al[i] + ps;
    }
    // rescale O accumulators
#pragma unroll
    for (int c = 0; c < 8; c++)
#pragma unroll
      for (int i = 0; i < 4; i++) oacc[c][i] *= al[i];
    // write P (C-layout) to per-wave LDS strip, read back in A-layout
    bf16* ps = Ps[wave];
#pragma unroll
    for (int blk = 0; blk < 4; blk++)
#pragma unroll
      for (int i = 0; i < 4; i++)
        *((unsigned short*)ps + (rq * 4 + i) * 72 + blk * 16 + cl) = f2b_bits(s_acc[blk][i]);
    v8s pa[2];
#pragma unroll
    for (int c = 0; c < 2; c++)
      pa[c] = *(const v8s*)&ps[cl * 72 + c * 32 + rq * 8];
    // O += P V : 8 d-blocks of 16
#pragma unroll
    for (int c = 0; c < 8; c++)
#pragma unroll
      for (int ch = 0; ch < 2; ch++) {
        v8s bv = *(const v8s*)&Vs[(c * 16 + cl) * 72 + ch * 32 + rq * 8];
        oacc[c] = __builtin_amdgcn_mfma_f32_16x16x32_bf16(pa[ch], bv, oacc[c], 0, 0, 0);
      }
  }
  // epilogue: z[t][n*896 + slot*128 + d] += O / l
#pragma unroll
  for (int c = 0; c < 8; c++) {
    const int d = c * 16 + cl;
#pragma unroll
    for (int i = 0; i < 4; i++) {
      const int t = qb * 64 + wave * 16 + rq * 4 + i;
      float* dst = z + ((size_t)(b * 1024 + t)) * 3584 + n * 896 + slot * 128 + d;
      *dst += oacc[c][i] / l_i[i];
    }
  }
}

// ---------------------------------------------------------------------------
extern "C" void kernel_launch(void* const* d_in, const int* in_sizes, int n_in,
                              void* d_out, int out_size, void* d_ws, size_t ws_size,
                              hipStream_t stream)
{
  const float* x        = (const float*)d_in[0];
  const int*   tptr     = (const int*)d_in[1];
  const float* enc_base = (const float*)d_in[2];
  const float* enc_A    = (const float*)d_in[3];
  const float* enc_B    = (const float*)d_in[4];
  const float* beta_p   = (const float*)d_in[5];
  const float* lnm_g    = (const float*)d_in[6];
  const float* lnm_b    = (const float*)d_in[7];
  const float* w1       = (const float*)d_in[8];
  const float* b1       = (const float*)d_in[9];
  const float* w2       = (const float*)d_in[10];
  const float* b2       = (const float*)d_in[11];
  const float* lna_g    = (const float*)d_in[12];
  const float* lna_b    = (const float*)d_in[13];
  const float* Wq       = (const float*)d_in[14];
  const float* Wk       = (const float*)d_in[15];
  const float* Wv       = (const float*)d_in[16];
  const float* dln_g    = (const float*)d_in[17];
  const float* dln_b    = (const float*)d_in[18];
  const float* down_w   = (const float*)d_in[19];
  const float* up_w     = (const float*)d_in[20];

  // workspace (148.77 MB, <= proven budget):
  // [0, 58720256)            z: 4096x3584 f32 residual stream
  // [58720256, 96468992)     regionA: h/r | act chunks | qkv (q,k normal; v normal then dead)
  // [96468992, 125829120)    bufb: zm/hin/c bf16; also V^T [12][128][4096] during attention
  // [125829120, 148766720)   bf16 weights: w1b, w2b, encBt, Wt
  char* ws = (char*)d_ws;
  float* z      = (float*)ws;
  bf16*  hbuf   = (bf16*)(ws + (size_t)58720256);
  bf16*  act    = (bf16*)(ws + (size_t)58720256);
  bf16*  qkv    = (bf16*)(ws + (size_t)58720256);
  bf16*  bufb   = (bf16*)(ws + (size_t)96468992);
  bf16*  w1b    = (bf16*)(ws + (size_t)125829120);
  bf16*  w2b    = (bf16*)(ws + (size_t)132251648);
  bf16*  encBt  = (bf16*)(ws + (size_t)138674176);
  bf16*  Wt     = (bf16*)(ws + (size_t)140509184);  // [3][12][128][896]

  dim3 blk(256);
  // --- weight conversion ---
  cvt_kernel<<<1568, blk, 0, stream>>>(w1, w1b, 3211264);
  cvt_kernel<<<1568, blk, 0, stream>>>(w2, w2b, 3211264);
  cvt_t_kernel<<<dim3(112, 8, 1), blk, 0, stream>>>(enc_B, encBt, 256, 3584);
  cvt_t_kernel<<<dim3(4, 28, 12), blk, 0, stream>>>(Wq, Wt,                      896, 128);
  cvt_t_kernel<<<dim3(4, 28, 12), blk, 0, stream>>>(Wk, Wt + (size_t)12*128*896, 896, 128);
  cvt_t_kernel<<<dim3(4, 28, 12), blk, 0, stream>>>(Wv, Wt + (size_t)24*128*896, 896, 128);

  // 1. z = broadcast4(x @ enc_base_w^T)
  mfma_gemm<float, float, EPI_BCAST4><<<dim3(7, 32), blk, 0, stream>>>(x, 1024, enc_base, 1024, z, 0, nullptr, nullptr, 1024);
  // 2. h = x @ enc_A_w^T
  mfma_gemm<float, float, EPI_BF16><<<dim3(2, 32), blk, 0, stream>>>(x, 1024, enc_A, 1024, hbuf, 256, nullptr, nullptr, 1024);
  // 3. z += beta * (h @ enc_Bt^T)
  mfma_gemm<bf16, bf16, EPI_AXPY><<<dim3(28, 32), blk, 0, stream>>>(hbuf, 256, encBt, 256, z, 3584, nullptr, beta_p, 256);
  // 5. zm = LN(z) over 896
  ln_kernel<<<dim3(16384), blk, 0, stream>>>(z, lnm_g, lnm_b, bufb, 896);
  // 6+7. mixer, 4 chunks
  for (int c = 0; c < 4; c++) {
    const size_t ro = (size_t)c * 4096;
    mfma_gemm<bf16, bf16, EPI_GELU><<<dim3(28, 32), blk, 0, stream>>>(bufb + ro * 896, 896, w1b, 896, act, 3584, b1, nullptr, 896);
    mfma_gemm<bf16, bf16, EPI_RESID><<<dim3(7, 32), blk, 0, stream>>>(act, 3584, w2b, 3584, z + ro * 896, 896, b2, nullptr, 3584);
  }
  // 8. hin = LN(z) over 896
  ln_kernel<<<dim3(16384), blk, 0, stream>>>(z, lna_g, lna_b, bufb, 896);
  // 9. q,k,v projections
  qkv_mfma<<<dim3(1, 32, 36), blk, 0, stream>>>(bufb, Wt, qkv, tptr);
  // 9b. transpose V -> V^T in bufb (hin dead after qkv_mfma)
  vt_kernel<<<dim3(64, 2, 12), blk, 0, stream>>>(qkv + (size_t)24 * 4096 * 128, bufb);
  // 10. MFMA flash attention, adds into z slots
  attn_mfma<<<dim3(16, 48), blk, 0, stream>>>(qkv, bufb, z, tptr);
  // 11. c = LN(z) over 3584 (overwrites V^T region)
  ln_kernel<<<dim3(4096), blk, 0, stream>>>(z, dln_g, dln_b, bufb, 3584);
  // 12. r = c @ dec_down_w^T
  mfma_gemm<bf16, float, EPI_BF16><<<dim3(2, 32), blk, 0, stream>>>(bufb, 3584, down_w, 3584, hbuf, 256, nullptr, nullptr, 3584);
  // 13. y = r @ dec_up_w^T -> out (f32)
  mfma_gemm<bf16, float, EPI_F32><<<dim3(8, 32), blk, 0, stream>>>(hbuf, 256, up_w, 256, (float*)d_out, 1024, nullptr, nullptr, 256);
}

// Round 5
// 1058.864 us; speedup vs baseline: 6.7733x; 1.2466x over previous
//
#include <hip/hip_runtime.h>
#include <hip/hip_bf16.h>
#include <math.h>

typedef __hip_bfloat16 bf16;
typedef __attribute__((ext_vector_type(8))) short v8s;
typedef __attribute__((ext_vector_type(4))) float v4f;

#define EPI_F32    0
#define EPI_BF16   1
#define EPI_GELU   2
#define EPI_RESID  3
#define EPI_BCAST4 4
#define EPI_AXPY   5
#define EPI_RESID0 6   // z += acc (no bias)

// ---------- bf16 helpers (bit-level, exact) ----------
__device__ __forceinline__ float bf_lo(unsigned int w) { return __uint_as_float(w << 16); }
__device__ __forceinline__ float bf_hi(unsigned int w) { return __uint_as_float(w & 0xffff0000u); }
__device__ __forceinline__ unsigned short f2b_bits(float f) {
  unsigned int u = __float_as_uint(f);
  unsigned int r = (u + 0x7fffu + ((u >> 16) & 1u)) >> 16;   // RTNE
  return (unsigned short)r;
}
__device__ __forceinline__ void unpack8(uint4 u, float* f) {
  unsigned int w0 = u.x, w1 = u.y, w2 = u.z, w3 = u.w;
  f[0] = bf_lo(w0); f[1] = bf_hi(w0);
  f[2] = bf_lo(w1); f[3] = bf_hi(w1);
  f[4] = bf_lo(w2); f[5] = bf_hi(w2);
  f[6] = bf_lo(w3); f[7] = bf_hi(w3);
}
__device__ __forceinline__ void load8(const float* p, float* f) {
  float4 a = ((const float4*)p)[0];
  float4 b = ((const float4*)p)[1];
  f[0] = a.x; f[1] = a.y; f[2] = a.z; f[3] = a.w;
  f[4] = b.x; f[5] = b.y; f[6] = b.z; f[7] = b.w;
}

// ---------- weight conversion kernels ----------
__global__ __launch_bounds__(256) void cvt_kernel(const float* __restrict__ src,
                                                  bf16* __restrict__ dst, int n)
{
  int i = (blockIdx.x * 256 + threadIdx.x) * 8;
  if (i >= n) return;
  float f[8]; load8(src + i, f);
  unsigned short us[8];
#pragma unroll
  for (int j = 0; j < 8; j++) us[j] = f2b_bits(f[j]);
  *(uint4*)((unsigned short*)dst + i) = *(uint4*)us;
}

// transpose-convert: src f32 (batch, R, C) -> dst bf16 (batch, C, R). R,C multiples of 32.
__global__ __launch_bounds__(256) void cvt_t_kernel(const float* __restrict__ src,
                                                    bf16* __restrict__ dst, int R, int C)
{
  __shared__ float tile[32][33];
  const int c0 = blockIdx.x * 32, r0 = blockIdx.y * 32;
  const size_t bo = (size_t)blockIdx.z * R * C;
  const int tx = threadIdx.x & 31, ty = threadIdx.x >> 5;  // ty 0..7
#pragma unroll
  for (int i = 0; i < 4; i++) {
    int r = ty * 4 + i;
    tile[r][tx] = src[bo + (size_t)(r0 + r) * C + c0 + tx];
  }
  __syncthreads();
#pragma unroll
  for (int i = 0; i < 4; i++) {
    int r = ty * 4 + i;
    *((unsigned short*)dst + bo + (size_t)(c0 + r) * R + r0 + tx) = f2b_bits(tile[tx][r]);
  }
}

// bf16 transpose: v [12][4096][128] -> vt [12][128][4096], 64x64 tiles via f32 LDS
__global__ __launch_bounds__(256) void vt_kernel(const bf16* __restrict__ v,
                                                 bf16* __restrict__ vt)
{
  __shared__ float tile[64][65];
  const int h = blockIdx.z;
  const int t0 = blockIdx.x * 64, d0 = blockIdx.y * 64;
  const bf16* src = v + (size_t)h * 4096 * 128;
  bf16* dst = vt + (size_t)h * 128 * 4096;
  const int tid = threadIdx.x;
#pragma unroll
  for (int tt = 0; tt < 2; tt++) {
    int s = tt * 256 + tid;
    int r = s >> 3, c0 = (s & 7) * 8;
    float f[8];
    uint4 u = *(const uint4*)(src + (size_t)(t0 + r) * 128 + d0 + c0);
    unpack8(u, f);
#pragma unroll
    for (int j = 0; j < 8; j++) tile[r][c0 + j] = f[j];
  }
  __syncthreads();
#pragma unroll
  for (int tt = 0; tt < 2; tt++) {
    int s = tt * 256 + tid;
    int dr = s >> 3, c0 = (s & 7) * 8;
    unsigned short us[8];
#pragma unroll
    for (int j = 0; j < 8; j++) us[j] = f2b_bits(tile[c0 + j][dr]);
    *(uint4*)((unsigned short*)dst + (size_t)(d0 + dr) * 4096 + t0 + c0) = *(uint4*)us;
  }
}

// ---------- MFMA GEMM core ----------
__device__ __forceinline__ void stage_tile(const bf16* __restrict__ src, int ld, int r0, int k0,
                                           bf16* lds, int tid)
{
#pragma unroll
  for (int t = 0; t < 2; t++) {
    int s = t * 256 + tid;
    int m = s >> 2, c = s & 3;
    uint4 u = *(const uint4*)(src + (size_t)(r0 + m) * ld + k0 + c * 8);
    *(uint4*)&lds[m * 40 + c * 8] = u;
  }
}
__device__ __forceinline__ void stage_tile(const float* __restrict__ src, int ld, int r0, int k0,
                                           bf16* lds, int tid)
{
#pragma unroll
  for (int t = 0; t < 2; t++) {
    int s = t * 256 + tid;
    int m = s >> 2, c = s & 3;
    float f[8]; load8(src + (size_t)(r0 + m) * ld + k0 + c * 8, f);
    unsigned short us[8];
#pragma unroll
    for (int j = 0; j < 8; j++) us[j] = f2b_bits(f[j]);
    *(uint4*)&lds[m * 40 + c * 8] = *(uint4*)us;
  }
}

template<typename TA, typename TB, int EPI>
__device__ void mfma_core(const TA* __restrict__ A, int lda,
                          const TB* __restrict__ B, int ldb,
                          void* __restrict__ C, int ldc,
                          const float* __restrict__ bias,
                          const float* __restrict__ beta_p,
                          int m0, int n0, int K)
{
  __shared__ bf16 As[128 * 40];
  __shared__ bf16 Bs[128 * 40];
  const int tid = threadIdx.x;
  const int lane = tid & 63, wave = tid >> 6;
  const int mw = (wave & 1) * 64, nw = (wave >> 1) * 64;
  const int row = lane & 15, kc = lane >> 4;

  v4f acc[4][4];
  const v4f vzero = {0.f, 0.f, 0.f, 0.f};
#pragma unroll
  for (int i = 0; i < 4; i++)
#pragma unroll
    for (int j = 0; j < 4; j++) acc[i][j] = vzero;

  for (int k0 = 0; k0 < K; k0 += 32) {
    stage_tile(A, lda, m0, k0, As, tid);
    stage_tile(B, ldb, n0, k0, Bs, tid);
    __syncthreads();
    v8s af[4], bfr[4];
#pragma unroll
    for (int i = 0; i < 4; i++)
      af[i] = *(const v8s*)&As[(mw + i * 16 + row) * 40 + kc * 8];
#pragma unroll
    for (int j = 0; j < 4; j++)
      bfr[j] = *(const v8s*)&Bs[(nw + j * 16 + row) * 40 + kc * 8];
#pragma unroll
    for (int i = 0; i < 4; i++)
#pragma unroll
      for (int j = 0; j < 4; j++)
        acc[i][j] = __builtin_amdgcn_mfma_f32_16x16x32_bf16(af[i], bfr[j], acc[i][j], 0, 0, 0);
    __syncthreads();
  }

  const int cl = lane & 15, rq = lane >> 4;
  const float beta = (EPI == EPI_AXPY) ? beta_p[0] : 0.f;
#pragma unroll
  for (int mi = 0; mi < 4; mi++) {
#pragma unroll
    for (int nj = 0; nj < 4; nj++) {
      const int col = n0 + nw + nj * 16 + cl;
#pragma unroll
      for (int i = 0; i < 4; i++) {
        const int r = m0 + mw + mi * 16 + rq * 4 + i;
        float v = acc[mi][nj][i];
        if (EPI == EPI_F32) {
          ((float*)C)[(size_t)r * ldc + col] = v;
        } else if (EPI == EPI_BF16) {
          ((unsigned short*)C)[(size_t)r * ldc + col] = f2b_bits(v);
        } else if (EPI == EPI_GELU) {
          v += bias[col];
          v = 0.5f * v * (1.f + erff(v * 0.70710678118654752f));
          ((unsigned short*)C)[(size_t)r * ldc + col] = f2b_bits(v);
        } else if (EPI == EPI_RESID) {
          float* Z = (float*)C;
          size_t idx = (size_t)r * ldc + col;
          Z[idx] = Z[idx] + v + bias[col];
        } else if (EPI == EPI_RESID0) {
          float* Z = (float*)C;
          size_t idx = (size_t)r * ldc + col;
          Z[idx] = Z[idx] + v;
        } else if (EPI == EPI_BCAST4) {
          float* Z = (float*)C;
#pragma unroll
          for (int rep = 0; rep < 4; rep++)
            Z[(size_t)r * 3584 + rep * 896 + col] = v;
        } else if (EPI == EPI_AXPY) {
          float* Z = (float*)C;
          size_t idx = (size_t)r * 3584 + col;
          Z[idx] = Z[idx] + beta * v;
        }
      }
    }
  }
}

template<typename TA, typename TB, int EPI>
__global__ __launch_bounds__(256) void mfma_gemm(const TA* __restrict__ A, int lda,
                                                 const TB* __restrict__ B, int ldb,
                                                 void* __restrict__ C, int ldc,
                                                 const float* __restrict__ bias,
                                                 const float* __restrict__ beta_p, int K)
{
  mfma_core<TA, TB, EPI>(A, lda, B, ldb, C, ldc, bias, beta_p,
                         blockIdx.y * 128, blockIdx.x * 128, K);
}

// ---------- batched QKV projection ----------
__global__ __launch_bounds__(256) void qkv_mfma(const bf16* __restrict__ hin,
                                                const bf16* __restrict__ Wt,
                                                bf16* __restrict__ qkv,
                                                const int* __restrict__ tptr)
{
  const int zb = blockIdx.z;
  const int type = zb / 12, rem = zb % 12, n = rem / 3, kh = rem % 3;
  const int phase = ((tptr[0] % 4) + 4) % 4;
  const int hid = (kh == 0) ? n
                : (kh == 1) ? 4 + (n + 2 * (phase & 1)) % 4
                            : 8 + (n + phase) % 4;
  const bf16* B = Wt + ((size_t)type * 12 + hid) * 128 * 896;
  bf16* out = qkv + ((size_t)type * 12 + n * 3 + kh) * 4096 * 128;
  mfma_core<bf16, bf16, EPI_BF16>(hin + n * 896, 3584, B, 896, out, 128,
                                  nullptr, nullptr, blockIdx.y * 128, 0, 896);
}

// ---------- LayerNorm rows of length D (f32 in, bf16 out) ----------
__global__ __launch_bounds__(256) void ln_kernel(const float* __restrict__ in,
                                                 const float* __restrict__ g,
                                                 const float* __restrict__ bsh,
                                                 bf16* __restrict__ out, int D)
{
  __shared__ float row[3584];
  __shared__ float red[256];
  const int tid = threadIdx.x;
  const size_t base = (size_t)blockIdx.x * D;
  float s = 0.f;
  for (int i = tid; i < D; i += 256) { float v = in[base + i]; row[i] = v; s += v; }
  red[tid] = s; __syncthreads();
  for (int o = 128; o > 0; o >>= 1) { if (tid < o) red[tid] += red[tid + o]; __syncthreads(); }
  const float mean = red[0] / (float)D;
  __syncthreads();
  s = 0.f;
  for (int i = tid; i < D; i += 256) { float d = row[i] - mean; s += d * d; }
  red[tid] = s; __syncthreads();
  for (int o = 128; o > 0; o >>= 1) { if (tid < o) red[tid] += red[tid + o]; __syncthreads(); }
  const float inv = rsqrtf(red[0] / (float)D + 1e-5f);
  for (int i = tid; i < D; i += 256) {
    float v = (row[i] - mean) * inv * g[i] + bsh[i];
    *((unsigned short*)out + base + i) = f2b_bits(v);
  }
}

// ---------- MFMA flash attention (unchanged, proven R4) ----------
__global__ __launch_bounds__(256) void attn_mfma(const bf16* __restrict__ qkv,
                                                 const bf16* __restrict__ vt,
                                                 float* __restrict__ z,
                                                 const int* __restrict__ tptr)
{
  __shared__ bf16 Ks[64 * 136];
  __shared__ bf16 Vs[128 * 72];
  __shared__ bf16 Ps[4][16 * 72];
  const int tid = threadIdx.x;
  const int lane = tid & 63, wave = tid >> 6;
  const int cl = lane & 15, rq = lane >> 4;
  const int qb = 15 - blockIdx.x;
  const int bnk = blockIdx.y;
  const int b = bnk / 12, rem = bnk % 12, n = rem / 3, kh = rem % 3;
  const int phase = ((tptr[0] % 4) + 4) % 4;
  const int slot = (kh == 0) ? 0 : (kh == 1) ? 1 + (phase & 1) : 3 + phase;
  const int head = n * 3 + kh;
  const size_t HS = (size_t)12 * 4096 * 128;
  const bf16* qp = qkv + ((size_t)head * 4096 + b * 1024) * 128;
  const bf16* kp = qkv + HS + ((size_t)head * 4096 + b * 1024) * 128;
  const bf16* vtp = vt + (size_t)head * 128 * 4096;

  v8s aq[4];
  {
    const bf16* qrow = qp + (size_t)(qb * 64 + wave * 16 + cl) * 128 + rq * 8;
#pragma unroll
    for (int c = 0; c < 4; c++) aq[c] = *(const v8s*)(qrow + c * 32);
  }
  v4f oacc[8];
  const v4f vzero = {0.f, 0.f, 0.f, 0.f};
#pragma unroll
  for (int c = 0; c < 8; c++) oacc[c] = vzero;
  float m_i[4] = {-1e30f, -1e30f, -1e30f, -1e30f};
  float l_i[4] = {0.f, 0.f, 0.f, 0.f};

  for (int kt = 0; kt <= qb; kt++) {
    __syncthreads();
#pragma unroll
    for (int t = 0; t < 4; t++) {
      int s = t * 256 + tid;
      int r = s >> 4, c0 = (s & 15) * 8;
      *(uint4*)&Ks[r * 136 + c0] = *(const uint4*)(kp + (size_t)(kt * 64 + r) * 128 + c0);
    }
#pragma unroll
    for (int t = 0; t < 4; t++) {
      int s = t * 256 + tid;
      int d = s >> 3, c0 = (s & 7) * 8;
      *(uint4*)&Vs[d * 72 + c0] =
          *(const uint4*)(vtp + (size_t)d * 4096 + b * 1024 + kt * 64 + c0);
    }
    __syncthreads();

    v4f s_acc[4];
#pragma unroll
    for (int blk = 0; blk < 4; blk++) {
      s_acc[blk] = vzero;
#pragma unroll
      for (int c = 0; c < 4; c++) {
        v8s bk = *(const v8s*)&Ks[(blk * 16 + cl) * 136 + c * 32 + rq * 8];
        s_acc[blk] = __builtin_amdgcn_mfma_f32_16x16x32_bf16(aq[c], bk, s_acc[blk], 0, 0, 0);
      }
    }
#pragma unroll
    for (int blk = 0; blk < 4; blk++)
#pragma unroll
      for (int i = 0; i < 4; i++) {
        float sv = s_acc[blk][i] * 0.088388347648318447f;
        if (kt == qb && (blk * 16 + cl) > (wave * 16 + rq * 4 + i)) sv = -1e30f;
        s_acc[blk][i] = sv;
      }
    float al[4];
#pragma unroll
    for (int i = 0; i < 4; i++) {
      float mx = fmaxf(fmaxf(s_acc[0][i], s_acc[1][i]), fmaxf(s_acc[2][i], s_acc[3][i]));
      mx = fmaxf(mx, __shfl_xor(mx, 1, 64));
      mx = fmaxf(mx, __shfl_xor(mx, 2, 64));
      mx = fmaxf(mx, __shfl_xor(mx, 4, 64));
      mx = fmaxf(mx, __shfl_xor(mx, 8, 64));
      const float mn = fmaxf(m_i[i], mx);
      al[i] = __expf(m_i[i] - mn);
      m_i[i] = mn;
      float ps = 0.f;
#pragma unroll
      for (int blk = 0; blk < 4; blk++) {
        float p = __expf(s_acc[blk][i] - mn);
        s_acc[blk][i] = p;
        ps += p;
      }
      ps += __shfl_xor(ps, 1, 64);
      ps += __shfl_xor(ps, 2, 64);
      ps += __shfl_xor(ps, 4, 64);
      ps += __shfl_xor(ps, 8, 64);
      l_i[i] = l_i[i] * al[i] + ps;
    }
#pragma unroll
    for (int c = 0; c < 8; c++)
#pragma unroll
      for (int i = 0; i < 4; i++) oacc[c][i] *= al[i];
    bf16* ps = Ps[wave];
#pragma unroll
    for (int blk = 0; blk < 4; blk++)
#pragma unroll
      for (int i = 0; i < 4; i++)
        *((unsigned short*)ps + (rq * 4 + i) * 72 + blk * 16 + cl) = f2b_bits(s_acc[blk][i]);
    v8s pa[2];
#pragma unroll
    for (int c = 0; c < 2; c++)
      pa[c] = *(const v8s*)&ps[cl * 72 + c * 32 + rq * 8];
#pragma unroll
    for (int c = 0; c < 8; c++)
#pragma unroll
      for (int ch = 0; ch < 2; ch++) {
        v8s bv = *(const v8s*)&Vs[(c * 16 + cl) * 72 + ch * 32 + rq * 8];
        oacc[c] = __builtin_amdgcn_mfma_f32_16x16x32_bf16(pa[ch], bv, oacc[c], 0, 0, 0);
      }
  }
#pragma unroll
  for (int c = 0; c < 8; c++) {
    const int d = c * 16 + cl;
#pragma unroll
    for (int i = 0; i < 4; i++) {
      const int t = qb * 64 + wave * 16 + rq * 4 + i;
      float* dst = z + ((size_t)(b * 1024 + t)) * 3584 + n * 896 + slot * 128 + d;
      *dst += oacc[c][i] / l_i[i];
    }
  }
}

// ---------------------------------------------------------------------------
extern "C" void kernel_launch(void* const* d_in, const int* in_sizes, int n_in,
                              void* d_out, int out_size, void* d_ws, size_t ws_size,
                              hipStream_t stream)
{
  const float* x        = (const float*)d_in[0];
  const int*   tptr     = (const int*)d_in[1];
  const float* enc_base = (const float*)d_in[2];
  const float* enc_A    = (const float*)d_in[3];
  const float* enc_B    = (const float*)d_in[4];
  const float* beta_p   = (const float*)d_in[5];
  const float* lnm_g    = (const float*)d_in[6];
  const float* lnm_b    = (const float*)d_in[7];
  const float* w1       = (const float*)d_in[8];
  const float* b1       = (const float*)d_in[9];
  const float* w2       = (const float*)d_in[10];
  const float* b2       = (const float*)d_in[11];
  const float* lna_g    = (const float*)d_in[12];
  const float* lna_b    = (const float*)d_in[13];
  const float* Wq       = (const float*)d_in[14];
  const float* Wk       = (const float*)d_in[15];
  const float* Wv       = (const float*)d_in[16];
  const float* dln_g    = (const float*)d_in[17];
  const float* dln_b    = (const float*)d_in[18];
  const float* down_w   = (const float*)d_in[19];
  const float* up_w     = (const float*)d_in[20];

  const bool big = (ws_size >= (size_t)228458496);
  char* ws = (char*)d_ws;
  float* z = (float*)ws;
  bf16 *hbuf, *act, *qkv, *bufb, *w1b, *w2b, *encBt, *Wt;
  if (big) {
    // [0,58.7M) z | [58.7,176.2M) act 117.4M (also hbuf early, qkv late)
    // [176.2,205.5M) bufb | [205.5,228.5M) weights
    hbuf  = (bf16*)(ws + (size_t)58720256);
    act   = (bf16*)(ws + (size_t)58720256);
    qkv   = (bf16*)(ws + (size_t)58720256);
    bufb  = (bf16*)(ws + (size_t)176160768);
    w1b   = (bf16*)(ws + (size_t)205520896);
    w2b   = (bf16*)(ws + (size_t)211943424);
    encBt = (bf16*)(ws + (size_t)218365952);
    Wt    = (bf16*)(ws + (size_t)220200960);
  } else {
    // proven 148.77MB layout
    hbuf  = (bf16*)(ws + (size_t)58720256);
    act   = (bf16*)(ws + (size_t)58720256);
    qkv   = (bf16*)(ws + (size_t)58720256);
    bufb  = (bf16*)(ws + (size_t)96468992);
    w1b   = (bf16*)(ws + (size_t)125829120);
    w2b   = (bf16*)(ws + (size_t)132251648);
    encBt = (bf16*)(ws + (size_t)138674176);
    Wt    = (bf16*)(ws + (size_t)140509184);
  }

  dim3 blk(256);
  // --- weight conversion ---
  cvt_kernel<<<1568, blk, 0, stream>>>(w1, w1b, 3211264);
  cvt_kernel<<<1568, blk, 0, stream>>>(w2, w2b, 3211264);
  cvt_t_kernel<<<dim3(112, 8, 1), blk, 0, stream>>>(enc_B, encBt, 256, 3584);
  cvt_t_kernel<<<dim3(4, 28, 12), blk, 0, stream>>>(Wq, Wt,                      896, 128);
  cvt_t_kernel<<<dim3(4, 28, 12), blk, 0, stream>>>(Wk, Wt + (size_t)12*128*896, 896, 128);
  cvt_t_kernel<<<dim3(4, 28, 12), blk, 0, stream>>>(Wv, Wt + (size_t)24*128*896, 896, 128);

  // 1. z = broadcast4(x @ enc_base_w^T)
  mfma_gemm<float, float, EPI_BCAST4><<<dim3(7, 32), blk, 0, stream>>>(x, 1024, enc_base, 1024, z, 0, nullptr, nullptr, 1024);
  // 2. h = x @ enc_A_w^T
  mfma_gemm<float, float, EPI_BF16><<<dim3(2, 32), blk, 0, stream>>>(x, 1024, enc_A, 1024, hbuf, 256, nullptr, nullptr, 1024);
  // 3. z += beta * (h @ enc_Bt^T)
  mfma_gemm<bf16, bf16, EPI_AXPY><<<dim3(28, 32), blk, 0, stream>>>(hbuf, 256, encBt, 256, z, 3584, nullptr, beta_p, 256);
  // 5. zm = LN(z) over 896
  ln_kernel<<<dim3(16384), blk, 0, stream>>>(z, lnm_g, lnm_b, bufb, 896);

  // 6+7. mixer
  if (big) {
    // one shot: act 16384x3584, grid density 14 WG/CU (GELU) & 3.5 WG/CU (RESID)
    mfma_gemm<bf16, bf16, EPI_GELU><<<dim3(28, 128), blk, 0, stream>>>(bufb, 896, w1b, 896, act, 3584, b1, nullptr, 896);
    mfma_gemm<bf16, bf16, EPI_RESID><<<dim3(7, 128), blk, 0, stream>>>(act, 3584, w2b, 3584, z, 896, b2, nullptr, 3584);
  } else {
    // N-chunked: act column blocks 16384x896; RESID accumulates z over K chunks
    for (int c = 0; c < 4; c++) {
      mfma_gemm<bf16, bf16, EPI_GELU><<<dim3(7, 128), blk, 0, stream>>>(
          bufb, 896, w1b + (size_t)c * 896 * 896, 896, act, 896, b1 + c * 896, nullptr, 896);
      if (c == 0)
        mfma_gemm<bf16, bf16, EPI_RESID><<<dim3(7, 128), blk, 0, stream>>>(
            act, 896, w2b + (size_t)c * 896, 3584, z, 896, b2, nullptr, 896);
      else
        mfma_gemm<bf16, bf16, EPI_RESID0><<<dim3(7, 128), blk, 0, stream>>>(
            act, 896, w2b + (size_t)c * 896, 3584, z, 896, nullptr, nullptr, 896);
    }
  }

  // 8. hin = LN(z) over 896
  ln_kernel<<<dim3(16384), blk, 0, stream>>>(z, lna_g, lna_b, bufb, 896);
  // 9. q,k,v projections
  qkv_mfma<<<dim3(1, 32, 36), blk, 0, stream>>>(bufb, Wt, qkv, tptr);
  // 9b. transpose V -> V^T in bufb (hin dead after qkv_mfma)
  vt_kernel<<<dim3(64, 2, 12), blk, 0, stream>>>(qkv + (size_t)24 * 4096 * 128, bufb);
  // 10. MFMA flash attention, adds into z slots
  attn_mfma<<<dim3(16, 48), blk, 0, stream>>>(qkv, bufb, z, tptr);
  // 11. c = LN(z) over 3584
  ln_kernel<<<dim3(4096), blk, 0, stream>>>(z, dln_g, dln_b, bufb, 3584);
  // 12. r = c @ dec_down_w^T
  mfma_gemm<bf16, float, EPI_BF16><<<dim3(2, 32), blk, 0, stream>>>(bufb, 3584, down_w, 3584, hbuf, 256, nullptr, nullptr, 3584);
  // 13. y = r @ dec_up_w^T -> out (f32)
  mfma_gemm<bf16, float, EPI_F32><<<dim3(8, 32), blk, 0, stream>>>(hbuf, 256, up_w, 256, (float*)d_out, 1024, nullptr, nullptr, 256);
}

// Round 6
// 1023.316 us; speedup vs baseline: 7.0086x; 1.0347x over previous
//
#include <hip/hip_runtime.h>
#include <hip/hip_bf16.h>
#include <math.h>

typedef __hip_bfloat16 bf16;
typedef __attribute__((ext_vector_type(8))) short v8s;
typedef __attribute__((ext_vector_type(4))) float v4f;

#define EPI_F32    0
#define EPI_BF16   1
#define EPI_GELU   2
#define EPI_RESID  3
#define EPI_BCAST4 4
#define EPI_AXPY   5
#define EPI_RESID0 6

// ---------- bf16 helpers ----------
__device__ __forceinline__ float bf_lo(unsigned int w) { return __uint_as_float(w << 16); }
__device__ __forceinline__ float bf_hi(unsigned int w) { return __uint_as_float(w & 0xffff0000u); }
__device__ __forceinline__ unsigned short f2b_bits(float f) {
  unsigned int u = __float_as_uint(f);
  unsigned int r = (u + 0x7fffu + ((u >> 16) & 1u)) >> 16;   // RTNE
  return (unsigned short)r;
}
__device__ __forceinline__ void unpack8(uint4 u, float* f) {
  unsigned int w0 = u.x, w1 = u.y, w2 = u.z, w3 = u.w;
  f[0] = bf_lo(w0); f[1] = bf_hi(w0);
  f[2] = bf_lo(w1); f[3] = bf_hi(w1);
  f[4] = bf_lo(w2); f[5] = bf_hi(w2);
  f[6] = bf_lo(w3); f[7] = bf_hi(w3);
}
__device__ __forceinline__ void load8(const float* p, float* f) {
  float4 a = ((const float4*)p)[0];
  float4 b = ((const float4*)p)[1];
  f[0] = a.x; f[1] = a.y; f[2] = a.z; f[3] = a.w;
  f[4] = b.x; f[5] = b.y; f[6] = b.z; f[7] = b.w;
}
// async 16B global->LDS (lds dest: wave-uniform base + lane*16)
__device__ __forceinline__ void gl_lds16(const void* g, void* l) {
  __builtin_amdgcn_global_load_lds(
      (__attribute__((address_space(1))) void*)g,
      (__attribute__((address_space(3))) void*)l, 16, 0, 0);
}

// ---------- weight conversion kernels ----------
__global__ __launch_bounds__(256) void cvt_kernel(const float* __restrict__ src,
                                                  bf16* __restrict__ dst, int n)
{
  int i = (blockIdx.x * 256 + threadIdx.x) * 8;
  if (i >= n) return;
  float f[8]; load8(src + i, f);
  unsigned short us[8];
#pragma unroll
  for (int j = 0; j < 8; j++) us[j] = f2b_bits(f[j]);
  *(uint4*)((unsigned short*)dst + i) = *(uint4*)us;
}

__global__ __launch_bounds__(256) void cvt_t_kernel(const float* __restrict__ src,
                                                    bf16* __restrict__ dst, int R, int C)
{
  __shared__ float tile[32][33];
  const int c0 = blockIdx.x * 32, r0 = blockIdx.y * 32;
  const size_t bo = (size_t)blockIdx.z * R * C;
  const int tx = threadIdx.x & 31, ty = threadIdx.x >> 5;
#pragma unroll
  for (int i = 0; i < 4; i++) {
    int r = ty * 4 + i;
    tile[r][tx] = src[bo + (size_t)(r0 + r) * C + c0 + tx];
  }
  __syncthreads();
#pragma unroll
  for (int i = 0; i < 4; i++) {
    int r = ty * 4 + i;
    *((unsigned short*)dst + bo + (size_t)(c0 + r) * R + r0 + tx) = f2b_bits(tile[tx][r]);
  }
}

// bf16 transpose: v [12][4096][128] -> vt [12][128][4096]
__global__ __launch_bounds__(256) void vt_kernel(const bf16* __restrict__ v,
                                                 bf16* __restrict__ vt)
{
  __shared__ float tile[64][65];
  const int h = blockIdx.z;
  const int t0 = blockIdx.x * 64, d0 = blockIdx.y * 64;
  const bf16* src = v + (size_t)h * 4096 * 128;
  bf16* dst = vt + (size_t)h * 128 * 4096;
  const int tid = threadIdx.x;
#pragma unroll
  for (int tt = 0; tt < 2; tt++) {
    int s = tt * 256 + tid;
    int r = s >> 3, c0 = (s & 7) * 8;
    float f[8];
    uint4 u = *(const uint4*)(src + (size_t)(t0 + r) * 128 + d0 + c0);
    unpack8(u, f);
#pragma unroll
    for (int j = 0; j < 8; j++) tile[r][c0 + j] = f[j];
  }
  __syncthreads();
#pragma unroll
  for (int tt = 0; tt < 2; tt++) {
    int s = tt * 256 + tid;
    int dr = s >> 3, c0 = (s & 7) * 8;
    unsigned short us[8];
#pragma unroll
    for (int j = 0; j < 8; j++) us[j] = f2b_bits(tile[c0 + j][dr]);
    *(uint4*)((unsigned short*)dst + (size_t)(d0 + dr) * 4096 + t0 + c0) = *(uint4*)us;
  }
}

// ---------- MFMA GEMM core, async-staged (m97 structure) ----------
// LDS tile 128x32 bf16, unpadded stride 32 (row = 64B). Staged as 8 segs of
// 1024B; wave w handles segs {2w, 2w+1}: lane i -> row seg*16+i/4, chunk i%4.
__device__ __forceinline__ void stage_async(const bf16* __restrict__ src, int ld, int r0, int k0,
                                            bf16* lds, int wave, int lane)
{
#pragma unroll
  for (int t = 0; t < 2; t++) {
    int seg = wave * 2 + t;
    const bf16* g = src + (size_t)(r0 + seg * 16 + (lane >> 2)) * ld + k0 + (lane & 3) * 8;
    gl_lds16(g, lds + seg * 512);
  }
}
__device__ __forceinline__ void stage_sync(const float* __restrict__ src, int ld, int r0, int k0,
                                           bf16* lds, int tid)
{
#pragma unroll
  for (int t = 0; t < 2; t++) {
    int s = t * 256 + tid;
    int m = s >> 2, c = s & 3;
    float f[8]; load8(src + (size_t)(r0 + m) * ld + k0 + c * 8, f);
    unsigned short us[8];
#pragma unroll
    for (int j = 0; j < 8; j++) us[j] = f2b_bits(f[j]);
    *(uint4*)&lds[m * 32 + c * 8] = *(uint4*)us;
  }
}
__device__ __forceinline__ void stage_tile(const bf16* __restrict__ src, int ld, int r0, int k0,
                                           bf16* lds, int tid, int wave, int lane)
{ stage_async(src, ld, r0, k0, lds, wave, lane); }
__device__ __forceinline__ void stage_tile(const float* __restrict__ src, int ld, int r0, int k0,
                                           bf16* lds, int tid, int wave, int lane)
{ stage_sync(src, ld, r0, k0, lds, tid); }

template<typename TA, typename TB, int EPI>
__device__ void mfma_core(const TA* __restrict__ A, int lda,
                          const TB* __restrict__ B, int ldb,
                          void* __restrict__ C, int ldc,
                          const float* __restrict__ bias,
                          const float* __restrict__ beta_p,
                          int m0, int n0, int K)
{
  __shared__ bf16 As[128 * 32];
  __shared__ bf16 Bs[128 * 32];
  const int tid = threadIdx.x;
  const int lane = tid & 63, wave = tid >> 6;
  const int mw = (wave & 1) * 64, nw = (wave >> 1) * 64;
  const int row = lane & 15, kc = lane >> 4;

  v4f acc[4][4];
  const v4f vzero = {0.f, 0.f, 0.f, 0.f};
#pragma unroll
  for (int i = 0; i < 4; i++)
#pragma unroll
    for (int j = 0; j < 4; j++) acc[i][j] = vzero;

  for (int k0 = 0; k0 < K; k0 += 32) {
    stage_tile(A, lda, m0, k0, As, tid, wave, lane);
    stage_tile(B, ldb, n0, k0, Bs, tid, wave, lane);
    __syncthreads();   // drains vmcnt (async LDS stores) + lgkm
    v8s af[4], bfr[4];
#pragma unroll
    for (int i = 0; i < 4; i++)
      af[i] = *(const v8s*)&As[(mw + i * 16 + row) * 32 + kc * 8];
#pragma unroll
    for (int j = 0; j < 4; j++)
      bfr[j] = *(const v8s*)&Bs[(nw + j * 16 + row) * 32 + kc * 8];
#pragma unroll
    for (int i = 0; i < 4; i++)
#pragma unroll
      for (int j = 0; j < 4; j++)
        acc[i][j] = __builtin_amdgcn_mfma_f32_16x16x32_bf16(af[i], bfr[j], acc[i][j], 0, 0, 0);
    __syncthreads();
  }

  const int cl = lane & 15, rq = lane >> 4;
  const float beta = (EPI == EPI_AXPY) ? beta_p[0] : 0.f;
#pragma unroll
  for (int mi = 0; mi < 4; mi++) {
#pragma unroll
    for (int nj = 0; nj < 4; nj++) {
      const int col = n0 + nw + nj * 16 + cl;
#pragma unroll
      for (int i = 0; i < 4; i++) {
        const int r = m0 + mw + mi * 16 + rq * 4 + i;
        float v = acc[mi][nj][i];
        if (EPI == EPI_F32) {
          ((float*)C)[(size_t)r * ldc + col] = v;
        } else if (EPI == EPI_BF16) {
          ((unsigned short*)C)[(size_t)r * ldc + col] = f2b_bits(v);
        } else if (EPI == EPI_GELU) {
          v += bias[col];
          v = 0.5f * v * (1.f + erff(v * 0.70710678118654752f));
          ((unsigned short*)C)[(size_t)r * ldc + col] = f2b_bits(v);
        } else if (EPI == EPI_RESID) {
          float* Z = (float*)C;
          size_t idx = (size_t)r * ldc + col;
          Z[idx] = Z[idx] + v + bias[col];
        } else if (EPI == EPI_RESID0) {
          float* Z = (float*)C;
          size_t idx = (size_t)r * ldc + col;
          Z[idx] = Z[idx] + v;
        } else if (EPI == EPI_BCAST4) {
          float* Z = (float*)C;
#pragma unroll
          for (int rep = 0; rep < 4; rep++)
            Z[(size_t)r * 3584 + rep * 896 + col] = v;
        } else if (EPI == EPI_AXPY) {
          float* Z = (float*)C;
          size_t idx = (size_t)r * 3584 + col;
          Z[idx] = Z[idx] + beta * v;
        }
      }
    }
  }
}

template<typename TA, typename TB, int EPI>
__global__ __launch_bounds__(256) void mfma_gemm(const TA* __restrict__ A, int lda,
                                                 const TB* __restrict__ B, int ldb,
                                                 void* __restrict__ C, int ldc,
                                                 const float* __restrict__ bias,
                                                 const float* __restrict__ beta_p, int K)
{
  mfma_core<TA, TB, EPI>(A, lda, B, ldb, C, ldc, bias, beta_p,
                         blockIdx.y * 128, blockIdx.x * 128, K);
}

// XCD-swizzled variant for M=16384 (128 M-blocks): xcd = lin&7 owns M-stripes
// [xcd*16, xcd*16+16) and sweeps N-blocks -> B-tile stays in that XCD's L2.
template<typename TA, typename TB, int EPI>
__global__ __launch_bounds__(256) void mfma_gemm_sw(const TA* __restrict__ A, int lda,
                                                    const TB* __restrict__ B, int ldb,
                                                    void* __restrict__ C, int ldc,
                                                    const float* __restrict__ bias,
                                                    const float* __restrict__ beta_p, int K)
{
  const int lin = blockIdx.x;
  const int m0 = ((((lin & 7) << 4) | ((lin >> 3) & 15))) * 128;
  const int n0 = (lin >> 7) * 128;
  mfma_core<TA, TB, EPI>(A, lda, B, ldb, C, ldc, bias, beta_p, m0, n0, K);
}

// ---------- batched QKV projection ----------
__global__ __launch_bounds__(256) void qkv_mfma(const bf16* __restrict__ hin,
                                                const bf16* __restrict__ Wt,
                                                bf16* __restrict__ qkv,
                                                const int* __restrict__ tptr)
{
  const int zb = blockIdx.z;
  const int type = zb / 12, rem = zb % 12, n = rem / 3, kh = rem % 3;
  const int phase = ((tptr[0] % 4) + 4) % 4;
  const int hid = (kh == 0) ? n
                : (kh == 1) ? 4 + (n + 2 * (phase & 1)) % 4
                            : 8 + (n + phase) % 4;
  const bf16* B = Wt + ((size_t)type * 12 + hid) * 128 * 896;
  bf16* out = qkv + ((size_t)type * 12 + n * 3 + kh) * 4096 * 128;
  mfma_core<bf16, bf16, EPI_BF16>(hin + n * 896, 3584, B, 896, out, 128,
                                  nullptr, nullptr, blockIdx.y * 128, 0, 896);
}

// ---------- LayerNorm ----------
__global__ __launch_bounds__(256) void ln_kernel(const float* __restrict__ in,
                                                 const float* __restrict__ g,
                                                 const float* __restrict__ bsh,
                                                 bf16* __restrict__ out, int D)
{
  __shared__ float row[3584];
  __shared__ float red[256];
  const int tid = threadIdx.x;
  const size_t base = (size_t)blockIdx.x * D;
  float s = 0.f;
  for (int i = tid; i < D; i += 256) { float v = in[base + i]; row[i] = v; s += v; }
  red[tid] = s; __syncthreads();
  for (int o = 128; o > 0; o >>= 1) { if (tid < o) red[tid] += red[tid + o]; __syncthreads(); }
  const float mean = red[0] / (float)D;
  __syncthreads();
  s = 0.f;
  for (int i = tid; i < D; i += 256) { float d = row[i] - mean; s += d * d; }
  red[tid] = s; __syncthreads();
  for (int o = 128; o > 0; o >>= 1) { if (tid < o) red[tid] += red[tid + o]; __syncthreads(); }
  const float inv = rsqrtf(red[0] / (float)D + 1e-5f);
  for (int i = tid; i < D; i += 256) {
    float v = (row[i] - mean) * inv * g[i] + bsh[i];
    *((unsigned short*)out + base + i) = f2b_bits(v);
  }
}

// ---------- MFMA flash attention (proven R4) ----------
__global__ __launch_bounds__(256) void attn_mfma(const bf16* __restrict__ qkv,
                                                 const bf16* __restrict__ vt,
                                                 float* __restrict__ z,
                                                 const int* __restrict__ tptr)
{
  __shared__ bf16 Ks[64 * 136];
  __shared__ bf16 Vs[128 * 72];
  __shared__ bf16 Ps[4][16 * 72];
  const int tid = threadIdx.x;
  const int lane = tid & 63, wave = tid >> 6;
  const int cl = lane & 15, rq = lane >> 4;
  const int qb = 15 - blockIdx.x;
  const int bnk = blockIdx.y;
  const int b = bnk / 12, rem = bnk % 12, n = rem / 3, kh = rem % 3;
  const int phase = ((tptr[0] % 4) + 4) % 4;
  const int slot = (kh == 0) ? 0 : (kh == 1) ? 1 + (phase & 1) : 3 + phase;
  const int head = n * 3 + kh;
  const size_t HS = (size_t)12 * 4096 * 128;
  const bf16* qp = qkv + ((size_t)head * 4096 + b * 1024) * 128;
  const bf16* kp = qkv + HS + ((size_t)head * 4096 + b * 1024) * 128;
  const bf16* vtp = vt + (size_t)head * 128 * 4096;

  v8s aq[4];
  {
    const bf16* qrow = qp + (size_t)(qb * 64 + wave * 16 + cl) * 128 + rq * 8;
#pragma unroll
    for (int c = 0; c < 4; c++) aq[c] = *(const v8s*)(qrow + c * 32);
  }
  v4f oacc[8];
  const v4f vzero = {0.f, 0.f, 0.f, 0.f};
#pragma unroll
  for (int c = 0; c < 8; c++) oacc[c] = vzero;
  float m_i[4] = {-1e30f, -1e30f, -1e30f, -1e30f};
  float l_i[4] = {0.f, 0.f, 0.f, 0.f};

  for (int kt = 0; kt <= qb; kt++) {
    __syncthreads();
#pragma unroll
    for (int t = 0; t < 4; t++) {
      int s = t * 256 + tid;
      int r = s >> 4, c0 = (s & 15) * 8;
      *(uint4*)&Ks[r * 136 + c0] = *(const uint4*)(kp + (size_t)(kt * 64 + r) * 128 + c0);
    }
#pragma unroll
    for (int t = 0; t < 4; t++) {
      int s = t * 256 + tid;
      int d = s >> 3, c0 = (s & 7) * 8;
      *(uint4*)&Vs[d * 72 + c0] =
          *(const uint4*)(vtp + (size_t)d * 4096 + b * 1024 + kt * 64 + c0);
    }
    __syncthreads();

    v4f s_acc[4];
#pragma unroll
    for (int blk = 0; blk < 4; blk++) {
      s_acc[blk] = vzero;
#pragma unroll
      for (int c = 0; c < 4; c++) {
        v8s bk = *(const v8s*)&Ks[(blk * 16 + cl) * 136 + c * 32 + rq * 8];
        s_acc[blk] = __builtin_amdgcn_mfma_f32_16x16x32_bf16(aq[c], bk, s_acc[blk], 0, 0, 0);
      }
    }
#pragma unroll
    for (int blk = 0; blk < 4; blk++)
#pragma unroll
      for (int i = 0; i < 4; i++) {
        float sv = s_acc[blk][i] * 0.088388347648318447f;
        if (kt == qb && (blk * 16 + cl) > (wave * 16 + rq * 4 + i)) sv = -1e30f;
        s_acc[blk][i] = sv;
      }
    float al[4];
#pragma unroll
    for (int i = 0; i < 4; i++) {
      float mx = fmaxf(fmaxf(s_acc[0][i], s_acc[1][i]), fmaxf(s_acc[2][i], s_acc[3][i]));
      mx = fmaxf(mx, __shfl_xor(mx, 1, 64));
      mx = fmaxf(mx, __shfl_xor(mx, 2, 64));
      mx = fmaxf(mx, __shfl_xor(mx, 4, 64));
      mx = fmaxf(mx, __shfl_xor(mx, 8, 64));
      const float mn = fmaxf(m_i[i], mx);
      al[i] = __expf(m_i[i] - mn);
      m_i[i] = mn;
      float ps = 0.f;
#pragma unroll
      for (int blk = 0; blk < 4; blk++) {
        float p = __expf(s_acc[blk][i] - mn);
        s_acc[blk][i] = p;
        ps += p;
      }
      ps += __shfl_xor(ps, 1, 64);
      ps += __shfl_xor(ps, 2, 64);
      ps += __shfl_xor(ps, 4, 64);
      ps += __shfl_xor(ps, 8, 64);
      l_i[i] = l_i[i] * al[i] + ps;
    }
#pragma unroll
    for (int c = 0; c < 8; c++)
#pragma unroll
      for (int i = 0; i < 4; i++) oacc[c][i] *= al[i];
    bf16* ps = Ps[wave];
#pragma unroll
    for (int blk = 0; blk < 4; blk++)
#pragma unroll
      for (int i = 0; i < 4; i++)
        *((unsigned short*)ps + (rq * 4 + i) * 72 + blk * 16 + cl) = f2b_bits(s_acc[blk][i]);
    v8s pa[2];
#pragma unroll
    for (int c = 0; c < 2; c++)
      pa[c] = *(const v8s*)&ps[cl * 72 + c * 32 + rq * 8];
#pragma unroll
    for (int c = 0; c < 8; c++)
#pragma unroll
      for (int ch = 0; ch < 2; ch++) {
        v8s bv = *(const v8s*)&Vs[(c * 16 + cl) * 72 + ch * 32 + rq * 8];
        oacc[c] = __builtin_amdgcn_mfma_f32_16x16x32_bf16(pa[ch], bv, oacc[c], 0, 0, 0);
      }
  }
#pragma unroll
  for (int c = 0; c < 8; c++) {
    const int d = c * 16 + cl;
#pragma unroll
    for (int i = 0; i < 4; i++) {
      const int t = qb * 64 + wave * 16 + rq * 4 + i;
      float* dst = z + ((size_t)(b * 1024 + t)) * 3584 + n * 896 + slot * 128 + d;
      *dst += oacc[c][i] / l_i[i];
    }
  }
}

// ---------------------------------------------------------------------------
extern "C" void kernel_launch(void* const* d_in, const int* in_sizes, int n_in,
                              void* d_out, int out_size, void* d_ws, size_t ws_size,
                              hipStream_t stream)
{
  const float* x        = (const float*)d_in[0];
  const int*   tptr     = (const int*)d_in[1];
  const float* enc_base = (const float*)d_in[2];
  const float* enc_A    = (const float*)d_in[3];
  const float* enc_B    = (const float*)d_in[4];
  const float* beta_p   = (const float*)d_in[5];
  const float* lnm_g    = (const float*)d_in[6];
  const float* lnm_b    = (const float*)d_in[7];
  const float* w1       = (const float*)d_in[8];
  const float* b1       = (const float*)d_in[9];
  const float* w2       = (const float*)d_in[10];
  const float* b2       = (const float*)d_in[11];
  const float* lna_g    = (const float*)d_in[12];
  const float* lna_b    = (const float*)d_in[13];
  const float* Wq       = (const float*)d_in[14];
  const float* Wk       = (const float*)d_in[15];
  const float* Wv       = (const float*)d_in[16];
  const float* dln_g    = (const float*)d_in[17];
  const float* dln_b    = (const float*)d_in[18];
  const float* down_w   = (const float*)d_in[19];
  const float* up_w     = (const float*)d_in[20];

  const bool big = (ws_size >= (size_t)228458496);
  char* ws = (char*)d_ws;
  float* z = (float*)ws;
  bf16 *hbuf, *act, *qkv, *bufb, *w1b, *w2b, *encBt, *Wt;
  if (big) {
    hbuf  = (bf16*)(ws + (size_t)58720256);
    act   = (bf16*)(ws + (size_t)58720256);
    qkv   = (bf16*)(ws + (size_t)58720256);
    bufb  = (bf16*)(ws + (size_t)176160768);
    w1b   = (bf16*)(ws + (size_t)205520896);
    w2b   = (bf16*)(ws + (size_t)211943424);
    encBt = (bf16*)(ws + (size_t)218365952);
    Wt    = (bf16*)(ws + (size_t)220200960);
  } else {
    hbuf  = (bf16*)(ws + (size_t)58720256);
    act   = (bf16*)(ws + (size_t)58720256);
    qkv   = (bf16*)(ws + (size_t)58720256);
    bufb  = (bf16*)(ws + (size_t)96468992);
    w1b   = (bf16*)(ws + (size_t)125829120);
    w2b   = (bf16*)(ws + (size_t)132251648);
    encBt = (bf16*)(ws + (size_t)138674176);
    Wt    = (bf16*)(ws + (size_t)140509184);
  }

  dim3 blk(256);
  // --- weight conversion ---
  cvt_kernel<<<1568, blk, 0, stream>>>(w1, w1b, 3211264);
  cvt_kernel<<<1568, blk, 0, stream>>>(w2, w2b, 3211264);
  cvt_t_kernel<<<dim3(112, 8, 1), blk, 0, stream>>>(enc_B, encBt, 256, 3584);
  cvt_t_kernel<<<dim3(4, 28, 12), blk, 0, stream>>>(Wq, Wt,                      896, 128);
  cvt_t_kernel<<<dim3(4, 28, 12), blk, 0, stream>>>(Wk, Wt + (size_t)12*128*896, 896, 128);
  cvt_t_kernel<<<dim3(4, 28, 12), blk, 0, stream>>>(Wv, Wt + (size_t)24*128*896, 896, 128);

  // 1. z = broadcast4(x @ enc_base_w^T)
  mfma_gemm<float, float, EPI_BCAST4><<<dim3(7, 32), blk, 0, stream>>>(x, 1024, enc_base, 1024, z, 0, nullptr, nullptr, 1024);
  // 2. h = x @ enc_A_w^T
  mfma_gemm<float, float, EPI_BF16><<<dim3(2, 32), blk, 0, stream>>>(x, 1024, enc_A, 1024, hbuf, 256, nullptr, nullptr, 1024);
  // 3. z += beta * (h @ enc_Bt^T)
  mfma_gemm<bf16, bf16, EPI_AXPY><<<dim3(28, 32), blk, 0, stream>>>(hbuf, 256, encBt, 256, z, 3584, nullptr, beta_p, 256);
  // 5. zm = LN(z) over 896
  ln_kernel<<<dim3(16384), blk, 0, stream>>>(z, lnm_g, lnm_b, bufb, 896);

  // 6+7. mixer
  if (big) {
    mfma_gemm_sw<bf16, bf16, EPI_GELU><<<dim3(3584), blk, 0, stream>>>(bufb, 896, w1b, 896, act, 3584, b1, nullptr, 896);
    mfma_gemm_sw<bf16, bf16, EPI_RESID><<<dim3(896), blk, 0, stream>>>(act, 3584, w2b, 3584, z, 896, b2, nullptr, 3584);
  } else {
    for (int c = 0; c < 4; c++) {
      mfma_gemm_sw<bf16, bf16, EPI_GELU><<<dim3(896), blk, 0, stream>>>(
          bufb, 896, w1b + (size_t)c * 896 * 896, 896, act, 896, b1 + c * 896, nullptr, 896);
      if (c == 0)
        mfma_gemm_sw<bf16, bf16, EPI_RESID><<<dim3(896), blk, 0, stream>>>(
            act, 896, w2b + (size_t)c * 896, 3584, z, 896, b2, nullptr, 896);
      else
        mfma_gemm_sw<bf16, bf16, EPI_RESID0><<<dim3(896), blk, 0, stream>>>(
            act, 896, w2b + (size_t)c * 896, 3584, z, 896, nullptr, nullptr, 896);
    }
  }

  // 8. hin = LN(z) over 896
  ln_kernel<<<dim3(16384), blk, 0, stream>>>(z, lna_g, lna_b, bufb, 896);
  // 9. q,k,v projections
  qkv_mfma<<<dim3(1, 32, 36), blk, 0, stream>>>(bufb, Wt, qkv, tptr);
  // 9b. transpose V -> V^T in bufb
  vt_kernel<<<dim3(64, 2, 12), blk, 0, stream>>>(qkv + (size_t)24 * 4096 * 128, bufb);
  // 10. MFMA flash attention, adds into z slots
  attn_mfma<<<dim3(16, 48), blk, 0, stream>>>(qkv, bufb, z, tptr);
  // 11. c = LN(z) over 3584
  ln_kernel<<<dim3(4096), blk, 0, stream>>>(z, dln_g, dln_b, bufb, 3584);
  // 12. r = c @ dec_down_w^T
  mfma_gemm<bf16, float, EPI_BF16><<<dim3(2, 32), blk, 0, stream>>>(bufb, 3584, down_w, 3584, hbuf, 256, nullptr, nullptr, 3584);
  // 13. y = r @ dec_up_w^T -> out (f32)
  mfma_gemm<bf16, float, EPI_F32><<<dim3(8, 32), blk, 0, stream>>>(hbuf, 256, up_w, 256, (float*)d_out, 1024, nullptr, nullptr, 256);
}